// Round 7
// baseline (656.741 us; speedup 1.0000x reference)
//
#include <hip/hip_runtime.h>

#define NN 32768
#define EE 262144

static __device__ __forceinline__ float sigm(float x){
  return 1.0f / (1.0f + __expf(-x));
}

// ---------------- node pass: o3-layernorm + src/dst linears ----------------
__global__ __launch_bounds__(256) void k_node(
    const float* __restrict__ node,
    const float* __restrict__ Wss, const float* __restrict__ Wsv,
    const float* __restrict__ Wds, const float* __restrict__ Wdv,
    float* __restrict__ ss, float* __restrict__ ds,
    float* __restrict__ sv, float* __restrict__ dv)
{
  int n = blockIdx.x * 256 + threadIdx.x;
  if (n >= NN) return;
  const float4* row = reinterpret_cast<const float4*>(node + (size_t)n * 80);
  float s[32], v[48];
#pragma unroll
  for (int i = 0; i < 8; ++i){
    float4 t = row[i];
    s[i*4+0]=t.x; s[i*4+1]=t.y; s[i*4+2]=t.z; s[i*4+3]=t.w;
  }
#pragma unroll
  for (int i = 0; i < 12; ++i){
    float4 t = row[8+i];
    v[i*4+0]=t.x; v[i*4+1]=t.y; v[i*4+2]=t.z; v[i*4+3]=t.w;
  }
  float mean = 0.f;
#pragma unroll
  for (int i=0;i<32;++i) mean += s[i];
  mean *= (1.0f/32.0f);
  float var = 0.f;
#pragma unroll
  for (int i=0;i<32;++i){ float d0 = s[i]-mean; var += d0*d0; }
  var *= (1.0f/32.0f);
  float sinv = rsqrtf(var + 1e-5f);
#pragma unroll
  for (int i=0;i<32;++i) s[i] = (s[i]-mean)*sinv;
  float n2 = 0.f;
#pragma unroll
  for (int i=0;i<48;++i) n2 += v[i]*v[i];
  n2 *= (1.0f/16.0f);
  float vinv = rsqrtf(n2 + 1e-5f);
#pragma unroll
  for (int i=0;i<48;++i) v[i] *= vinv;

  float* ssr = ss + (size_t)n*32;
  float* dsr = ds + (size_t)n*32;
#pragma unroll 1
  for (int d=0; d<32; ++d){
    float a=0.f, b=0.f;
#pragma unroll
    for (int c=0;c<32;++c){ a += s[c]*Wss[c*32+d]; b += s[c]*Wds[c*32+d]; }
    ssr[d]=a; dsr[d]=b;
  }
  float* svr = sv + (size_t)n*48;
  float* dvr = dv + (size_t)n*48;
#pragma unroll 1
  for (int d=0; d<16; ++d){
#pragma unroll
    for (int x=0;x<3;++x){
      float a=0.f, b=0.f;
#pragma unroll
      for (int c=0;c<16;++c){ a += v[c*3+x]*Wsv[c*16+d]; b += v[c*3+x]*Wdv[c*16+d]; }
      svr[d*3+x]=a; dvr[d*3+x]=b;
    }
  }
}

// ---------------- CSR build ----------------
__global__ __launch_bounds__(256) void k_hist(const int* __restrict__ ei, int* __restrict__ deg){
  int e = blockIdx.x*256 + threadIdx.x;
  if (e >= EE) return;
  atomicAdd(deg + ei[EE + e], 1);
}

__global__ __launch_bounds__(1024) void k_scan(const int* __restrict__ deg,
                                               int* __restrict__ base, int* __restrict__ cursor){
  __shared__ int lds[1024];
  int t = threadIdx.x;
  int v[32];
#pragma unroll
  for (int i=0;i<32;++i) v[i] = deg[t*32+i];
  int run = 0;
#pragma unroll
  for (int i=0;i<32;++i){ int x=v[i]; v[i]=run; run+=x; }
  lds[t]=run; __syncthreads();
  for (int off=1; off<1024; off<<=1){
    int add = (t>=off) ? lds[t-off] : 0;
    __syncthreads();
    lds[t] += add;
    __syncthreads();
  }
  int pre = (t==0) ? 0 : lds[t-1];
#pragma unroll
  for (int i=0;i<32;++i){ int b = pre + v[i]; base[t*32+i]=b; cursor[t*32+i]=b; }
}

__global__ __launch_bounds__(256) void k_scatter(const int* __restrict__ ei,
                                                 int* __restrict__ cursor, int* __restrict__ csr){
  int e = blockIdx.x*256 + threadIdx.x;
  if (e >= EE) return;
  int d = ei[EE + e];
  int pos = atomicAdd(cursor + d, 1);
  csr[pos] = e;
}

// ============== cooperative edge pass A: attention logits ==================
#define A_RBFA 0
#define A_RBFD 640
#define A_WA   960
#define A_ADOT 4288
#define A_EDG  4352
#define A_ESTR 152

__global__ __launch_bounds__(512) void k_edgeA2(
    const int* __restrict__ ei,
    const float* __restrict__ rbf, const float* __restrict__ rsh,
    const float* __restrict__ Wrbf, const float* __restrict__ Wa,
    const float* __restrict__ adot,
    const float* __restrict__ ss, const float* __restrict__ ds,
    const float* __restrict__ sv, const float* __restrict__ dv,
    float* __restrict__ logits)
{
  __shared__ __align__(16) float SH[A_EDG + 16*A_ESTR];
  const int t = threadIdx.x;
  for (int i=t; i<32*16; i+=512){ int row=i>>4, j=i&15; SH[A_RBFA+row*20+j] = Wrbf[j*112+row]; }
  for (int i=t; i<16*16; i+=512){ int row=i>>4, j=i&15; SH[A_RBFD+row*20+j] = Wrbf[j*112+80+row]; }
  for (int i=t; i<64*48; i+=512){ int o=i/48, k=i-48*o; SH[A_WA+o*52+k] = Wa[k*64+o]; }
  for (int i=t; i<64;    i+=512){ SH[A_ADOT+i] = adot[i]; }
  __syncthreads();

  const int g = t >> 5;
  const int c = t & 31;
  float* E = &SH[A_EDG + g*A_ESTR];
  const float IS3 = 0.57735026918962576f;

#pragma unroll 1
  for (int tile=0; tile<16; ++tile){
    const int e = blockIdx.x*256 + tile*16 + g;
    const int src = ei[e], dst = ei[EE + e];

    if (c < 8){
      float4 a = *reinterpret_cast<const float4*>(ss + (size_t)src*32 + c*4);
      float4 b = *reinterpret_cast<const float4*>(ds + (size_t)dst*32 + c*4);
      float4 o; o.x=a.x+b.x; o.y=a.y+b.y; o.z=a.z+b.z; o.w=a.w+b.w;
      *reinterpret_cast<float4*>(&E[c*4]) = o;
    } else if (c < 20){
      int i = c-8;
      float4 a = *reinterpret_cast<const float4*>(sv + (size_t)src*48 + i*4);
      float4 b = *reinterpret_cast<const float4*>(dv + (size_t)dst*48 + i*4);
      float4 o; o.x=a.x+b.x; o.y=a.y+b.y; o.z=a.z+b.z; o.w=a.w+b.w;
      *reinterpret_cast<float4*>(&E[32+i*4]) = o;
    } else if (c < 24){
      int i = c-20;
      *reinterpret_cast<float4*>(&E[80+i*4]) =
          *reinterpret_cast<const float4*>(rbf + (size_t)e*16 + i*4);
    } else if (c == 24){
      *reinterpret_cast<float4*>(&E[96]) =
          *reinterpret_cast<const float4*>(rsh + (size_t)e*4);
    }

    float rr[16];
#pragma unroll
    for (int i=0;i<4;++i) *reinterpret_cast<float4*>(&rr[i*4]) =
        *reinterpret_cast<const float4*>(&E[80+i*4]);
    const float y0=E[96], y1x=E[97], y1y=E[98], y1z=E[99];
    {
      float wA=0.f;
#pragma unroll
      for (int j4=0;j4<4;++j4){
        float4 a0 = *reinterpret_cast<const float4*>(&SH[A_RBFA + c*20 + j4*4]);
        wA += rr[j4*4+0]*a0.x + rr[j4*4+1]*a0.y + rr[j4*4+2]*a0.z + rr[j4*4+3]*a0.w;
      }
      E[104+c] = wA * E[c] * y0;
    }
    if (c < 16){
      float wD=0.f;
#pragma unroll
      for (int j4=0;j4<4;++j4){
        float4 a0 = *reinterpret_cast<const float4*>(&SH[A_RBFD + c*20 + j4*4]);
        wD += rr[j4*4+0]*a0.x + rr[j4*4+1]*a0.y + rr[j4*4+2]*a0.z + rr[j4*4+3]*a0.w;
      }
      float vx=E[32+c*3], vy=E[33+c*3], vz=E[34+c*3];
      E[136+c] = wD * (vx*y1x + vy*y1y + vz*y1z) * IS3;
    }

    float mm[48];
#pragma unroll
    for (int k4=0;k4<12;++k4) *reinterpret_cast<float4*>(&mm[k4*4]) =
        *reinterpret_cast<const float4*>(&E[104+k4*4]);
    float acc0=0.f, acc1=0.f;
#pragma unroll
    for (int k4=0;k4<12;++k4){
      float4 w0 = *reinterpret_cast<const float4*>(&SH[A_WA + c*52 + k4*4]);
      float4 w1 = *reinterpret_cast<const float4*>(&SH[A_WA + (32+c)*52 + k4*4]);
      acc0 += mm[k4*4+0]*w0.x + mm[k4*4+1]*w0.y + mm[k4*4+2]*w0.z + mm[k4*4+3]*w0.w;
      acc1 += mm[k4*4+0]*w1.x + mm[k4*4+1]*w1.y + mm[k4*4+2]*w1.z + mm[k4*4+3]*w1.w;
    }
    acc0 = ((acc0 > 0.f) ? acc0 : 0.2f*acc0) * SH[A_ADOT+c];
    acc1 = ((acc1 > 0.f) ? acc1 : 0.2f*acc1) * SH[A_ADOT+32+c];
#pragma unroll
    for (int msk=8; msk>=1; msk>>=1){
      acc0 += __shfl_xor(acc0, msk);
      acc1 += __shfl_xor(acc1, msk);
    }
    if ((c & 15) == 0){
      int h0 = c >> 4;
      logits[(size_t)e*4 + h0]     = acc0;
      logits[(size_t)e*4 + 2 + h0] = acc1;
    }
  }
}

// ------------- per-(dst,head) softmax stats via CSR (no atomics) ----------
__global__ __launch_bounds__(256) void k_soft(
    const int* __restrict__ base, const int* __restrict__ deg,
    const int* __restrict__ csr, const float* __restrict__ logits,
    float* __restrict__ m, float* __restrict__ iden)
{
  int id = blockIdx.x*256 + threadIdx.x;
  if (id >= NN*4) return;
  int d = id >> 2, h = id & 3;
  int b = base[d], n = deg[d];
  float mm = -3.4e38f;
  for (int i=0;i<n;++i){ int e = csr[b+i]; mm = fmaxf(mm, logits[(size_t)e*4+h]); }
  float s = 0.f;
  for (int i=0;i<n;++i){ int e = csr[b+i]; s += __expf(logits[(size_t)e*4+h] - mm); }
  m[id] = mm;
  iden[id] = (n>0) ? 1.0f/s : 0.f;
}

// ============ edge value pass, part A: through SiLU/gating ================
// Writes 88 floats/edge into wflat row (stride 96), in CSR order:
//   [0:32) vsg  [32:80) vvg(gated)  [80:84) alpha  [84:88) y
#define CA_RBF  0      // [112][20]
#define CA_VALS 2240   // [32][52]
#define CA_VVA  3904   // [16][36]
#define CA_VVB  4480   // [16][20]
#define CA_VVC  4800   // [16][20]
#define CA_G    5120   // [16][36]
#define CA_EDG  5696
#define CA_ESTR 400

__global__ __launch_bounds__(256) void k_edgeCa(
    const int* __restrict__ csr, const int* __restrict__ ei,
    const float* __restrict__ rbf, const float* __restrict__ rsh,
    const float* __restrict__ Wrbf,
    const float* __restrict__ Wvals, const float* __restrict__ Wvalv,
    const float* __restrict__ Wg,
    const float* __restrict__ ss, const float* __restrict__ ds,
    const float* __restrict__ sv, const float* __restrict__ dv,
    const float* __restrict__ logits, const float* __restrict__ m,
    const float* __restrict__ iden, float* __restrict__ wflat)
{
  __shared__ __align__(16) float SH[CA_EDG + 8*CA_ESTR];
  const int t = threadIdx.x;
  for (int i=t; i<112*16; i+=256){ int d=i>>4, k=i&15; SH[CA_RBF+d*20+k]  = Wrbf[k*112+d]; }
  for (int i=t; i<32*48;  i+=256){ int d=i/48, k=i-48*d; SH[CA_VALS+d*52+k] = Wvals[k*32+d]; }
  for (int i=t; i<16*32;  i+=256){ int d=i>>5, k=i&31; SH[CA_VVA+d*36+k]  = Wvalv[k*16+d]; }
  for (int i=t; i<16*16;  i+=256){ int d=i>>4, k=i&15; SH[CA_VVB+d*20+k]  = Wvalv[(32+k)*16+d]; }
  for (int i=t; i<16*16;  i+=256){ int d=i>>4, k=i&15; SH[CA_VVC+d*20+k]  = Wvalv[(48+k)*16+d]; }
  for (int i=t; i<16*32;  i+=256){ int d=i>>5, k=i&31; SH[CA_G+d*36+k]    = Wg[k*16+d]; }
  __syncthreads();

  const int g = t >> 5;
  const int c = t & 31;
  float* E = &SH[CA_EDG + g*CA_ESTR];
  const float IS3 = 0.57735026918962576f;
  const float IS2 = 0.70710678118654752f;

#pragma unroll 1
  for (int tile=0; tile<16; ++tile){
    const int pidx = blockIdx.x*128 + tile*8 + g;
    const int e = csr[pidx];
    const int src = ei[e], dst = ei[EE + e];

    if (c < 8){
      float4 a = *reinterpret_cast<const float4*>(ss + (size_t)src*32 + c*4);
      float4 b = *reinterpret_cast<const float4*>(ds + (size_t)dst*32 + c*4);
      float4 o; o.x=a.x+b.x; o.y=a.y+b.y; o.z=a.z+b.z; o.w=a.w+b.w;
      *reinterpret_cast<float4*>(&E[c*4]) = o;
    } else if (c < 20){
      int i = c-8;
      float4 a = *reinterpret_cast<const float4*>(sv + (size_t)src*48 + i*4);
      float4 b = *reinterpret_cast<const float4*>(dv + (size_t)dst*48 + i*4);
      float4 o; o.x=a.x+b.x; o.y=a.y+b.y; o.z=a.z+b.z; o.w=a.w+b.w;
      *reinterpret_cast<float4*>(&E[32+i*4]) = o;
    } else if (c < 24){
      int i = c-20;
      *reinterpret_cast<float4*>(&E[80+i*4]) =
          *reinterpret_cast<const float4*>(rbf + (size_t)e*16 + i*4);
    } else if (c == 24){
      *reinterpret_cast<float4*>(&E[96]) =
          *reinterpret_cast<const float4*>(rsh + (size_t)e*4);
    } else if (c == 25){
      float4 l4 = *reinterpret_cast<const float4*>(logits + (size_t)e*4);
      float4 m4 = *reinterpret_cast<const float4*>(m + (size_t)dst*4);
      float4 i4 = *reinterpret_cast<const float4*>(iden + (size_t)dst*4);
      E[100] = __expf(l4.x-m4.x)*i4.x;
      E[101] = __expf(l4.y-m4.y)*i4.y;
      E[102] = __expf(l4.z-m4.z)*i4.z;
      E[103] = __expf(l4.w-m4.w)*i4.w;
    }

    float rr[16];
#pragma unroll
    for (int i=0;i<4;++i) *reinterpret_cast<float4*>(&rr[i*4]) =
        *reinterpret_cast<const float4*>(&E[80+i*4]);
    float wA=0.f, wB=0.f, wC=0.f, wD=0.f;
#pragma unroll
    for (int j4=0;j4<4;++j4){
      float4 a0 = *reinterpret_cast<const float4*>(&SH[CA_RBF + c*20           + j4*4]);
      float4 a1 = *reinterpret_cast<const float4*>(&SH[CA_RBF + (32+c)*20      + j4*4]);
      float4 a2 = *reinterpret_cast<const float4*>(&SH[CA_RBF + (64+c)*20      + j4*4]);
      float4 a3 = *reinterpret_cast<const float4*>(&SH[CA_RBF + (96+(c&15))*20 + j4*4]);
      float r0=rr[j4*4+0], r1=rr[j4*4+1], r2=rr[j4*4+2], r3=rr[j4*4+3];
      wA += r0*a0.x + r1*a0.y + r2*a0.z + r3*a0.w;
      wB += r0*a1.x + r1*a1.y + r2*a1.z + r3*a1.w;
      wC += r0*a2.x + r1*a2.y + r2*a2.z + r3*a2.w;
      wD += r0*a3.x + r1*a3.y + r2*a3.z + r3*a3.w;
    }

    const float y0=E[96], y1x=E[97], y1y=E[98], y1z=E[99];
    const float s_c = E[c];
    E[104+c] = wA * s_c * y0;
    E[152+c] = wB * s_c;
    if (c >= 16){
      int k = c-16;
      float vx=E[32+k*3], vy=E[33+k*3], vz=E[34+k*3];
      E[136+k] = wC * (vx*y1x+vy*y1y+vz*y1z) * IS3;
    }
    if (c < 16){
      int k = c;
      float vx=E[32+k*3], vy=E[33+k*3], vz=E[34+k*3];
      float u = wC * y0;
      E[200+k]    = u*vx; E[216+k] = u*vy; E[232+k] = u*vz;
      float cx=(vy*y1z - vz*y1y)*IS2;
      float cy=(vz*y1x - vx*y1z)*IS2;
      float cz=(vx*y1y - vy*y1x)*IS2;
      E[248+k]    = wD*cx; E[264+k] = wD*cy; E[280+k] = wD*cz;
    }

    if (c < 16){
      float acc=0.f, accB=0.f;
#pragma unroll
      for (int k4=0;k4<8;k4+=2){
        float4 w0 = *reinterpret_cast<const float4*>(&SH[CA_VVA + c*36 + k4*4]);
        float4 t0 = *reinterpret_cast<const float4*>(&E[152+k4*4]);
        float4 w1 = *reinterpret_cast<const float4*>(&SH[CA_VVA + c*36 + k4*4+4]);
        float4 t1 = *reinterpret_cast<const float4*>(&E[152+k4*4+4]);
        acc  += w0.x*t0.x + w0.y*t0.y + w0.z*t0.z + w0.w*t0.w;
        accB += w1.x*t1.x + w1.y*t1.y + w1.z*t1.z + w1.w*t1.w;
      }
      E[184+c]=acc+accB;
    }

    {
      int d0=c/3, x0=c-3*d0;
      float acc0 = E[184+d0]*E[97+x0];
#pragma unroll
      for (int k4=0;k4<4;++k4){
        float4 wb = *reinterpret_cast<const float4*>(&SH[CA_VVB + d0*20 + k4*4]);
        float4 wc = *reinterpret_cast<const float4*>(&SH[CA_VVC + d0*20 + k4*4]);
        float4 pp = *reinterpret_cast<const float4*>(&E[200 + x0*16 + k4*4]);
        float4 qq = *reinterpret_cast<const float4*>(&E[248 + x0*16 + k4*4]);
        acc0 += pp.x*wb.x+pp.y*wb.y+pp.z*wb.z+pp.w*wb.w
              + qq.x*wc.x+qq.y*wc.y+qq.z*wc.z+qq.w*wc.w;
      }
      E[344+c]=acc0;
      if (c < 16){
        int l=32+c, d1=l/3, x1=l-3*d1;
        float acc1 = E[184+d1]*E[97+x1];
#pragma unroll
        for (int k4=0;k4<4;++k4){
          float4 wb = *reinterpret_cast<const float4*>(&SH[CA_VVB + d1*20 + k4*4]);
          float4 wc = *reinterpret_cast<const float4*>(&SH[CA_VVC + d1*20 + k4*4]);
          float4 pp = *reinterpret_cast<const float4*>(&E[200 + x1*16 + k4*4]);
          float4 qq = *reinterpret_cast<const float4*>(&E[248 + x1*16 + k4*4]);
          acc1 += pp.x*wb.x+pp.y*wb.y+pp.z*wb.z+pp.w*wb.w
                + qq.x*wc.x+qq.y*wc.y+qq.z*wc.z+qq.w*wc.w;
        }
        E[344+l]=acc1;
      }
    }

    float accv=0.f, accw=0.f;
#pragma unroll
    for (int k4=0;k4<12;k4+=2){
      float4 w0 = *reinterpret_cast<const float4*>(&SH[CA_VALS + c*52 + k4*4]);
      float4 m0 = *reinterpret_cast<const float4*>(&E[104+k4*4]);
      float4 w1 = *reinterpret_cast<const float4*>(&SH[CA_VALS + c*52 + k4*4+4]);
      float4 m1 = *reinterpret_cast<const float4*>(&E[104+k4*4+4]);
      accv += w0.x*m0.x + w0.y*m0.y + w0.z*m0.z + w0.w*m0.w;
      accw += w1.x*m1.x + w1.y*m1.y + w1.z*m1.z + w1.w*m1.w;
    }
    accv += accw;
    E[296+c]=accv;

    if (c < 16){
      float acc=0.f;
#pragma unroll
      for (int k4=0;k4<8;++k4){
        float4 ww = *reinterpret_cast<const float4*>(&SH[CA_G + c*36 + k4*4]);
        float4 vv4 = *reinterpret_cast<const float4*>(&E[296+k4*4]);
        acc += ww.x*vv4.x + ww.y*vv4.y + ww.z*vv4.z + ww.w*vv4.w;
      }
      E[328+c]=sigm(acc);
    }

    float* erow = wflat + (size_t)pidx*96;
    erow[c] = accv * sigm(accv);
    erow[32+c] = E[344+c]*E[328+c/3];
    if (c < 16){
      int l = 32+c;
      erow[64+c] = E[344+l]*E[328+l/3];
    }
    if (c < 8){
      erow[80+c] = (c<4) ? E[100+c] : E[96+c-4];
    }
  }
}

// ===== edge value pass, part B: per-DST group, fused gather, no atomics ====
// One 32-lane group per destination node; loops over its deg consecutive
// CSR rows, accumulates the 5 owned output channels in registers, writes
// agg row exactly once (no memset, no atomics).
#define CB_VLS  0      // [64][52]
#define CB_VLVA 3328   // [32][36]
#define CB_VLVB 4480   // [32][20]
#define CB_VLVC 5120   // [32][20]
#define CB_W2   5760   // [112]
#define CB_EDG  5872
#define CB_ESTR 240
// E: 0:vvg[48] 48:a[4] 52:y[4] 56:vs2[48] 104:t2[32]
//    136:p2x[16] 152:p2y 168:p2z 184:q2x 200:q2y 216:q2z

__global__ __launch_bounds__(256) void k_edgeCb(
    const int* __restrict__ base, const int* __restrict__ deg,
    const float* __restrict__ Wvls, const float* __restrict__ Wvlv,
    const float* __restrict__ w2, const float* __restrict__ wflat,
    float* __restrict__ agg)
{
  __shared__ __align__(16) float SH[CB_EDG + 8*CB_ESTR];
  const int t = threadIdx.x;
  for (int i=t; i<64*48; i+=256){ int d=i/48, k=i-48*d; SH[CB_VLS+d*52+k] = Wvls[k*64+d]; }
  for (int i=t; i<32*32; i+=256){ int d=i>>5, k=i&31; SH[CB_VLVA+d*36+k] = Wvlv[k*32+d]; }
  for (int i=t; i<32*16; i+=256){ int d=i>>4, k=i&15; SH[CB_VLVB+d*20+k] = Wvlv[(32+k)*32+d]; }
  for (int i=t; i<32*16; i+=256){ int d=i>>4, k=i&15; SH[CB_VLVC+d*20+k] = Wvlv[(48+k)*32+d]; }
  for (int i=t; i<112;   i+=256){ SH[CB_W2+i] = w2[i]; }
  __syncthreads();

  const int g = t >> 5;
  const int c = t & 31;
  const int dst = blockIdx.x*8 + g;
  float* E = &SH[CB_EDG + g*CB_ESTR];
  const float IS3 = 0.57735026918962576f;
  const float IS2 = 0.70710678118654752f;

  const int b = base[dst];
  const int n = deg[dst];
  float ac0=0.f, ac1=0.f, ac2=0.f, ac3=0.f, ac4=0.f;

#pragma unroll 1
  for (int i=0; i<n; ++i){
    const float* wrow = wflat + (size_t)(b+i)*96;

    const float vsc = wrow[c];
    E[c] = wrow[32+c];
    if (c < 16) E[32+c] = wrow[64+c];
    if (c < 8)  E[48+c] = wrow[80+c];

    const float y0=E[52], y1x=E[53], y1y=E[54], y1z=E[55];

    E[104+c] = SH[CB_W2+32+c]*vsc;
    E[56+c]  = SH[CB_W2+c]*vsc*y0;
    if (c >= 16){
      int k = c-16;
      float gx=E[k*3], gy=E[k*3+1], gz=E[k*3+2];
      E[88+k] = SH[CB_W2+80+k]*(gx*y1x+gy*y1y+gz*y1z)*IS3;
    }
    if (c < 16){
      int k = c;
      float gx=E[k*3], gy=E[k*3+1], gz=E[k*3+2];
      float u = SH[CB_W2+64+k]*y0;
      E[136+k]=u*gx; E[152+k]=u*gy; E[168+k]=u*gz;
      float cx=(gy*y1z - gz*y1y)*IS2;
      float cy=(gz*y1x - gx*y1z)*IS2;
      float cz=(gx*y1y - gy*y1x)*IS2;
      float wq = SH[CB_W2+96+k];
      E[184+k]=wq*cx; E[200+k]=wq*cy; E[216+k]=wq*cz;
    }

    const float a0=E[48], a1=E[49], a2h=E[50], a3h=E[51];

    {
      float f0a=0.f, f0b=0.f, f1a=0.f, f1b=0.f;
#pragma unroll
      for (int k4=0;k4<12;k4+=2){
        float4 v0 = *reinterpret_cast<const float4*>(&E[56+k4*4]);
        float4 v1 = *reinterpret_cast<const float4*>(&E[56+k4*4+4]);
        float4 wa0 = *reinterpret_cast<const float4*>(&SH[CB_VLS + c*52 + k4*4]);
        float4 wa1 = *reinterpret_cast<const float4*>(&SH[CB_VLS + c*52 + k4*4+4]);
        float4 wb0 = *reinterpret_cast<const float4*>(&SH[CB_VLS + (32+c)*52 + k4*4]);
        float4 wb1 = *reinterpret_cast<const float4*>(&SH[CB_VLS + (32+c)*52 + k4*4+4]);
        f0a += v0.x*wa0.x + v0.y*wa0.y + v0.z*wa0.z + v0.w*wa0.w;
        f0b += v1.x*wa1.x + v1.y*wa1.y + v1.z*wa1.z + v1.w*wa1.w;
        f1a += v0.x*wb0.x + v0.y*wb0.y + v0.z*wb0.z + v0.w*wb0.w;
        f1b += v1.x*wb1.x + v1.y*wb1.y + v1.z*wb1.z + v1.w*wb1.w;
      }
      ac0 += (f0a+f0b)*a0;
      ac1 += (f1a+f1b)*((c<8)?a0:a1);
    }

    {
      float A2=0.f, A2b=0.f;
#pragma unroll
      for (int k4=0;k4<8;k4+=2){
        float4 w0 = *reinterpret_cast<const float4*>(&SH[CB_VLVA + c*36 + k4*4]);
        float4 t0 = *reinterpret_cast<const float4*>(&E[104+k4*4]);
        float4 w1 = *reinterpret_cast<const float4*>(&SH[CB_VLVA + c*36 + k4*4+4]);
        float4 t1 = *reinterpret_cast<const float4*>(&E[104+k4*4+4]);
        A2  += w0.x*t0.x + w0.y*t0.y + w0.z*t0.z + w0.w*t0.w;
        A2b += w1.x*t1.x + w1.y*t1.y + w1.z*t1.z + w1.w*t1.w;
      }
      A2 += A2b;
      float b0=A2*y1x, b1=A2*y1y, b2=A2*y1z;
#pragma unroll
      for (int k4=0;k4<4;++k4){
        float4 wb = *reinterpret_cast<const float4*>(&SH[CB_VLVB + c*20 + k4*4]);
        float4 wc = *reinterpret_cast<const float4*>(&SH[CB_VLVC + c*20 + k4*4]);
        float4 pp0 = *reinterpret_cast<const float4*>(&E[136 + k4*4]);
        float4 pp1 = *reinterpret_cast<const float4*>(&E[152 + k4*4]);
        float4 pp2 = *reinterpret_cast<const float4*>(&E[168 + k4*4]);
        float4 qq0 = *reinterpret_cast<const float4*>(&E[184 + k4*4]);
        float4 qq1 = *reinterpret_cast<const float4*>(&E[200 + k4*4]);
        float4 qq2 = *reinterpret_cast<const float4*>(&E[216 + k4*4]);
        b0 += pp0.x*wb.x+pp0.y*wb.y+pp0.z*wb.z+pp0.w*wb.w + qq0.x*wc.x+qq0.y*wc.y+qq0.z*wc.z+qq0.w*wc.w;
        b1 += pp1.x*wb.x+pp1.y*wb.y+pp1.z*wb.z+pp1.w*wb.w + qq1.x*wc.x+qq1.y*wc.y+qq1.z*wc.z+qq1.w*wc.w;
        b2 += pp2.x*wb.x+pp2.y*wb.y+pp2.z*wb.z+pp2.w*wb.w + qq2.x*wc.x+qq2.y*wc.y+qq2.z*wc.z+qq2.w*wc.w;
      }
      int o = 64 + c*3;
      float aw0 = (o   < 80) ? a1 : ((o   < 120) ? a2h : a3h);
      float aw1 = (o+1 < 80) ? a1 : ((o+1 < 120) ? a2h : a3h);
      float aw2 = (o+2 < 80) ? a1 : ((o+2 < 120) ? a2h : a3h);
      ac2 += b0*aw0;
      ac3 += b1*aw1;
      ac4 += b2*aw2;
    }
  }

  float* ar = agg + (size_t)dst*160;
  ar[c]      = ac0;
  ar[32+c]   = ac1;
  ar[64+c*3] = ac2;
  ar[65+c*3] = ac3;
  ar[66+c*3] = ac4;
}

// ------------- output pass: Wp projections + residual ----------------------
__global__ __launch_bounds__(256) void k_out(
    const float* __restrict__ node, const float* __restrict__ agg,
    const float* __restrict__ Wps, const float* __restrict__ Wpv,
    float* __restrict__ out)
{
  int n = blockIdx.x * 256 + threadIdx.x;
  if (n >= NN) return;
  const float* ar = agg + (size_t)n*160;
  const float* nr = node + (size_t)n*80;
  float* orow = out + (size_t)n*80;

  float a[64];
  { const float4* ap = reinterpret_cast<const float4*>(ar);
#pragma unroll
    for (int i=0;i<16;++i){ float4 t=ap[i];
      a[i*4]=t.x; a[i*4+1]=t.y; a[i*4+2]=t.z; a[i*4+3]=t.w; } }
#pragma unroll 1
  for (int d=0; d<32; ++d){
    float acc=0.f;
#pragma unroll
    for (int c=0;c<64;++c) acc += a[c]*Wps[c*32+d];
    orow[d] = nr[d] + acc;
  }
  float b[96];
  { const float4* bp = reinterpret_cast<const float4*>(ar + 64);
#pragma unroll
    for (int i=0;i<24;++i){ float4 t=bp[i];
      b[i*4]=t.x; b[i*4+1]=t.y; b[i*4+2]=t.z; b[i*4+3]=t.w; } }
#pragma unroll 1
  for (int d=0; d<16; ++d){
#pragma unroll
    for (int x=0;x<3;++x){
      float acc=0.f;
#pragma unroll
      for (int c=0;c<32;++c) acc += b[c*3+x]*Wpv[c*16+d];
      orow[32+d*3+x] = nr[32+d*3+x] + acc;
    }
  }
}

extern "C" void kernel_launch(void* const* d_in, const int* in_sizes, int n_in,
                              void* d_out, int out_size, void* d_ws, size_t ws_size,
                              hipStream_t stream)
{
  const float* node   = (const float*)d_in[0];
  const float* rbf    = (const float*)d_in[1];
  const float* rsh    = (const float*)d_in[2];
  const float* Wsrc_s = (const float*)d_in[3];
  const float* Wsrc_v = (const float*)d_in[4];
  const float* Wdst_s = (const float*)d_in[5];
  const float* Wdst_v = (const float*)d_in[6];
  const float* W_rbf  = (const float*)d_in[7];
  const float* dtp2   = (const float*)d_in[8];
  const float* Wa     = (const float*)d_in[9];
  const float* adot   = (const float*)d_in[10];
  const float* Wval_s = (const float*)d_in[11];
  const float* Wval_v = (const float*)d_in[12];
  const float* Wg     = (const float*)d_in[13];
  const float* Wvl_s  = (const float*)d_in[14];
  const float* Wvl_v  = (const float*)d_in[15];
  const float* Wp_s   = (const float*)d_in[16];
  const float* Wp_v   = (const float*)d_in[17];
  const int*   ei     = (const int*)d_in[18];

  float* ws = (float*)d_ws;

  size_t off = 0;
  float* ss   = ws + off; off += (size_t)NN*32;
  float* ds   = ws + off; off += (size_t)NN*32;
  float* sv   = ws + off; off += (size_t)NN*48;
  float* dv   = ws + off; off += (size_t)NN*48;
  float* lg   = ws + off; off += (size_t)EE*4;
  float* m    = ws + off; off += (size_t)NN*4;
  float* iden = ws + off; off += (size_t)NN*4;
  int* deg    = (int*)(ws + off); off += (size_t)NN;
  int* base   = (int*)(ws + off); off += (size_t)NN;
  int* cursor = (int*)(ws + off); off += (size_t)NN;
  int* csr    = (int*)(ws + off); off += (size_t)EE;
  float* agg  = ws + off; off += (size_t)NN*160;
  float* wflat= ws + off; off += (size_t)EE*96;
  size_t need_new = off * sizeof(float);
  if (ws_size < need_new) return;

  hipMemsetAsync(deg, 0, (size_t)NN*sizeof(int), stream);
  k_node   <<<NN/256, 256, 0, stream>>>(node, Wsrc_s, Wsrc_v, Wdst_s, Wdst_v, ss, ds, sv, dv);
  k_hist   <<<EE/256, 256, 0, stream>>>(ei, deg);
  k_scan   <<<1, 1024, 0, stream>>>(deg, base, cursor);
  k_scatter<<<EE/256, 256, 0, stream>>>(ei, cursor, csr);
  k_edgeA2 <<<EE/256, 512, 0, stream>>>(ei, rbf, rsh, W_rbf, Wa, adot, ss, ds, sv, dv, lg);
  k_soft   <<<(NN*4)/256, 256, 0, stream>>>(base, deg, csr, lg, m, iden);
  k_edgeCa <<<EE/128, 256, 0, stream>>>(csr, ei, rbf, rsh, W_rbf, Wval_s, Wval_v, Wg,
                                        ss, ds, sv, dv, lg, m, iden, wflat);
  k_edgeCb <<<NN/8, 256, 0, stream>>>(base, deg, Wvl_s, Wvl_v, dtp2, wflat, agg);
  k_out    <<<NN/256, 256, 0, stream>>>(node, agg, Wp_s, Wp_v, (float*)d_out);
}

// Round 8
// 536.510 us; speedup vs baseline: 1.2241x; 1.2241x over previous
//
#include <hip/hip_runtime.h>

#define NN 32768
#define EE 262144

static __device__ __forceinline__ float sigm(float x){
  return 1.0f / (1.0f + __expf(-x));
}
static __device__ __forceinline__ float dot4(float4 a, float4 b){
  return a.x*b.x + a.y*b.y + a.z*b.z + a.w*b.w;
}

// ---------------- node pass: o3-layernorm + src/dst linears ----------------
__global__ __launch_bounds__(256) void k_node(
    const float* __restrict__ node,
    const float* __restrict__ Wss, const float* __restrict__ Wsv,
    const float* __restrict__ Wds, const float* __restrict__ Wdv,
    float* __restrict__ ss, float* __restrict__ ds,
    float* __restrict__ sv, float* __restrict__ dv)
{
  int n = blockIdx.x * 256 + threadIdx.x;
  if (n >= NN) return;
  const float4* row = reinterpret_cast<const float4*>(node + (size_t)n * 80);
  float s[32], v[48];
#pragma unroll
  for (int i = 0; i < 8; ++i){
    float4 t = row[i];
    s[i*4+0]=t.x; s[i*4+1]=t.y; s[i*4+2]=t.z; s[i*4+3]=t.w;
  }
#pragma unroll
  for (int i = 0; i < 12; ++i){
    float4 t = row[8+i];
    v[i*4+0]=t.x; v[i*4+1]=t.y; v[i*4+2]=t.z; v[i*4+3]=t.w;
  }
  float mean = 0.f;
#pragma unroll
  for (int i=0;i<32;++i) mean += s[i];
  mean *= (1.0f/32.0f);
  float var = 0.f;
#pragma unroll
  for (int i=0;i<32;++i){ float d0 = s[i]-mean; var += d0*d0; }
  var *= (1.0f/32.0f);
  float sinv = rsqrtf(var + 1e-5f);
#pragma unroll
  for (int i=0;i<32;++i) s[i] = (s[i]-mean)*sinv;
  float n2 = 0.f;
#pragma unroll
  for (int i=0;i<48;++i) n2 += v[i]*v[i];
  n2 *= (1.0f/16.0f);
  float vinv = rsqrtf(n2 + 1e-5f);
#pragma unroll
  for (int i=0;i<48;++i) v[i] *= vinv;

  float* ssr = ss + (size_t)n*32;
  float* dsr = ds + (size_t)n*32;
#pragma unroll 1
  for (int d=0; d<32; ++d){
    float a=0.f, b=0.f;
#pragma unroll
    for (int c=0;c<32;++c){ a += s[c]*Wss[c*32+d]; b += s[c]*Wds[c*32+d]; }
    ssr[d]=a; dsr[d]=b;
  }
  float* svr = sv + (size_t)n*48;
  float* dvr = dv + (size_t)n*48;
#pragma unroll 1
  for (int d=0; d<16; ++d){
#pragma unroll
    for (int x=0;x<3;++x){
      float a=0.f, b=0.f;
#pragma unroll
      for (int c=0;c<16;++c){ a += v[c*3+x]*Wsv[c*16+d]; b += v[c*3+x]*Wdv[c*16+d]; }
      svr[d*3+x]=a; dvr[d*3+x]=b;
    }
  }
}

// ---------------- CSR build ----------------
__global__ __launch_bounds__(256) void k_hist(const int* __restrict__ ei, int* __restrict__ deg){
  int e = blockIdx.x*256 + threadIdx.x;
  if (e >= EE) return;
  atomicAdd(deg + ei[EE + e], 1);
}

__global__ __launch_bounds__(1024) void k_scan(const int* __restrict__ deg,
                                               int* __restrict__ base, int* __restrict__ cursor){
  __shared__ int lds[1024];
  int t = threadIdx.x;
  int v[32];
#pragma unroll
  for (int i=0;i<32;++i) v[i] = deg[t*32+i];
  int run = 0;
#pragma unroll
  for (int i=0;i<32;++i){ int x=v[i]; v[i]=run; run+=x; }
  lds[t]=run; __syncthreads();
  for (int off=1; off<1024; off<<=1){
    int add = (t>=off) ? lds[t-off] : 0;
    __syncthreads();
    lds[t] += add;
    __syncthreads();
  }
  int pre = (t==0) ? 0 : lds[t-1];
#pragma unroll
  for (int i=0;i<32;++i){ int b = pre + v[i]; base[t*32+i]=b; cursor[t*32+i]=b; }
}

__global__ __launch_bounds__(256) void k_scatter(const int* __restrict__ ei,
                                                 int* __restrict__ cursor, int* __restrict__ csr){
  int e = blockIdx.x*256 + threadIdx.x;
  if (e >= EE) return;
  int d = ei[EE + e];
  int pos = atomicAdd(cursor + d, 1);
  csr[pos] = e;
}

// ============== cooperative edge pass A: 2 edges per 32-lane group =========
#define A_RBFA 0      // [32][20]
#define A_RBFD 640    // [16][20]
#define A_WA   960    // [64][52]
#define A_ADOT 4288
#define A_EDG  4352
#define A_ESTR 152
// E: 0:s_[32] 32:v_[48] 80:r[16] 96:y[4] 104:ms[48]

__global__ __launch_bounds__(512) void k_edgeA2(
    const int* __restrict__ ei,
    const float* __restrict__ rbf, const float* __restrict__ rsh,
    const float* __restrict__ Wrbf, const float* __restrict__ Wa,
    const float* __restrict__ adot,
    const float* __restrict__ ss, const float* __restrict__ ds,
    const float* __restrict__ sv, const float* __restrict__ dv,
    float* __restrict__ logits)
{
  __shared__ __align__(16) float SH[A_EDG + 32*A_ESTR];
  const int t = threadIdx.x;
  for (int i=t; i<32*16; i+=512){ int row=i>>4, j=i&15; SH[A_RBFA+row*20+j] = Wrbf[j*112+row]; }
  for (int i=t; i<16*16; i+=512){ int row=i>>4, j=i&15; SH[A_RBFD+row*20+j] = Wrbf[j*112+80+row]; }
  for (int i=t; i<64*48; i+=512){ int o=i/48, k=i-48*o; SH[A_WA+o*52+k] = Wa[k*64+o]; }
  for (int i=t; i<64;    i+=512){ SH[A_ADOT+i] = adot[i]; }
  __syncthreads();

  const int g = t >> 5;
  const int c = t & 31;
  float* E0 = &SH[A_EDG + (2*g)*A_ESTR];
  float* E1 = E0 + A_ESTR;
  const float IS3 = 0.57735026918962576f;

#pragma unroll 1
  for (int tile=0; tile<8; ++tile){
    const int e0 = blockIdx.x*256 + tile*32 + 2*g;
    const int e1 = e0 + 1;
    const int s0i = ei[e0], d0i = ei[EE + e0];
    const int s1i = ei[e1], d1i = ei[EE + e1];

    // stage both edges
    if (c < 8){
      float4 a = *reinterpret_cast<const float4*>(ss + (size_t)s0i*32 + c*4);
      float4 b = *reinterpret_cast<const float4*>(ds + (size_t)d0i*32 + c*4);
      float4 o; o.x=a.x+b.x; o.y=a.y+b.y; o.z=a.z+b.z; o.w=a.w+b.w;
      *reinterpret_cast<float4*>(&E0[c*4]) = o;
      float4 a2 = *reinterpret_cast<const float4*>(ss + (size_t)s1i*32 + c*4);
      float4 b2 = *reinterpret_cast<const float4*>(ds + (size_t)d1i*32 + c*4);
      float4 o2; o2.x=a2.x+b2.x; o2.y=a2.y+b2.y; o2.z=a2.z+b2.z; o2.w=a2.w+b2.w;
      *reinterpret_cast<float4*>(&E1[c*4]) = o2;
    } else if (c < 20){
      int i = c-8;
      float4 a = *reinterpret_cast<const float4*>(sv + (size_t)s0i*48 + i*4);
      float4 b = *reinterpret_cast<const float4*>(dv + (size_t)d0i*48 + i*4);
      float4 o; o.x=a.x+b.x; o.y=a.y+b.y; o.z=a.z+b.z; o.w=a.w+b.w;
      *reinterpret_cast<float4*>(&E0[32+i*4]) = o;
      float4 a2 = *reinterpret_cast<const float4*>(sv + (size_t)s1i*48 + i*4);
      float4 b2 = *reinterpret_cast<const float4*>(dv + (size_t)d1i*48 + i*4);
      float4 o2; o2.x=a2.x+b2.x; o2.y=a2.y+b2.y; o2.z=a2.z+b2.z; o2.w=a2.w+b2.w;
      *reinterpret_cast<float4*>(&E1[32+i*4]) = o2;
    } else if (c < 24){
      int i = c-20;
      *reinterpret_cast<float4*>(&E0[80+i*4]) =
          *reinterpret_cast<const float4*>(rbf + (size_t)e0*16 + i*4);
      *reinterpret_cast<float4*>(&E1[80+i*4]) =
          *reinterpret_cast<const float4*>(rbf + (size_t)e1*16 + i*4);
    } else if (c == 24){
      *reinterpret_cast<float4*>(&E0[96]) =
          *reinterpret_cast<const float4*>(rsh + (size_t)e0*4);
      *reinterpret_cast<float4*>(&E1[96]) =
          *reinterpret_cast<const float4*>(rsh + (size_t)e1*4);
    }

    // phase 1: ms for both edges, weights read once
    float rr0[16], rr1[16];
#pragma unroll
    for (int i=0;i<4;++i){
      *reinterpret_cast<float4*>(&rr0[i*4]) = *reinterpret_cast<const float4*>(&E0[80+i*4]);
      *reinterpret_cast<float4*>(&rr1[i*4]) = *reinterpret_cast<const float4*>(&E1[80+i*4]);
    }
    const float ya0=E0[96], yax=E0[97], yay=E0[98], yaz=E0[99];
    const float yb0=E1[96], ybx=E1[97], yby=E1[98], ybz=E1[99];
    {
      float wA0=0.f, wA1=0.f;
#pragma unroll
      for (int j4=0;j4<4;++j4){
        float4 w = *reinterpret_cast<const float4*>(&SH[A_RBFA + c*20 + j4*4]);
        float4 r0 = *reinterpret_cast<const float4*>(&rr0[j4*4]);
        float4 r1 = *reinterpret_cast<const float4*>(&rr1[j4*4]);
        wA0 += dot4(r0,w); wA1 += dot4(r1,w);
      }
      E0[104+c] = wA0 * E0[c] * ya0;
      E1[104+c] = wA1 * E1[c] * yb0;
    }
    if (c < 16){
      float wD0=0.f, wD1=0.f;
#pragma unroll
      for (int j4=0;j4<4;++j4){
        float4 w = *reinterpret_cast<const float4*>(&SH[A_RBFD + c*20 + j4*4]);
        float4 r0 = *reinterpret_cast<const float4*>(&rr0[j4*4]);
        float4 r1 = *reinterpret_cast<const float4*>(&rr1[j4*4]);
        wD0 += dot4(r0,w); wD1 += dot4(r1,w);
      }
      float vx=E0[32+c*3], vy=E0[33+c*3], vz=E0[34+c*3];
      E0[136+c] = wD0 * (vx*yax + vy*yay + vz*yaz) * IS3;
      float ux=E1[32+c*3], uy=E1[33+c*3], uz=E1[34+c*3];
      E1[136+c] = wD1 * (ux*ybx + uy*yby + uz*ybz) * IS3;
    }

    // phase 2: logits, WA rows read once per pair
    float a00=0.f, a01=0.f, a10=0.f, a11=0.f;
#pragma unroll
    for (int k4=0;k4<12;++k4){
      float4 w0 = *reinterpret_cast<const float4*>(&SH[A_WA + c*52 + k4*4]);
      float4 w1 = *reinterpret_cast<const float4*>(&SH[A_WA + (32+c)*52 + k4*4]);
      float4 m0 = *reinterpret_cast<const float4*>(&E0[104+k4*4]);
      float4 m1 = *reinterpret_cast<const float4*>(&E1[104+k4*4]);
      a00 += dot4(m0,w0); a01 += dot4(m0,w1);
      a10 += dot4(m1,w0); a11 += dot4(m1,w1);
    }
    const float ad0 = SH[A_ADOT+c], ad1 = SH[A_ADOT+32+c];
    a00 = ((a00 > 0.f) ? a00 : 0.2f*a00) * ad0;
    a01 = ((a01 > 0.f) ? a01 : 0.2f*a01) * ad1;
    a10 = ((a10 > 0.f) ? a10 : 0.2f*a10) * ad0;
    a11 = ((a11 > 0.f) ? a11 : 0.2f*a11) * ad1;
#pragma unroll
    for (int msk=8; msk>=1; msk>>=1){
      a00 += __shfl_xor(a00, msk);
      a01 += __shfl_xor(a01, msk);
      a10 += __shfl_xor(a10, msk);
      a11 += __shfl_xor(a11, msk);
    }
    if ((c & 15) == 0){
      int h0 = c >> 4;
      logits[(size_t)e0*4 + h0]     = a00;
      logits[(size_t)e0*4 + 2 + h0] = a01;
      logits[(size_t)e1*4 + h0]     = a10;
      logits[(size_t)e1*4 + 2 + h0] = a11;
    }
  }
}

// ------------- per-(dst,head) softmax stats via CSR (no atomics) ----------
__global__ __launch_bounds__(256) void k_soft(
    const int* __restrict__ base, const int* __restrict__ deg,
    const int* __restrict__ csr, const float* __restrict__ logits,
    float* __restrict__ m, float* __restrict__ iden)
{
  int id = blockIdx.x*256 + threadIdx.x;
  if (id >= NN*4) return;
  int d = id >> 2, h = id & 3;
  int b = base[d], n = deg[d];
  float mm = -3.4e38f;
  for (int i=0;i<n;++i){ int e = csr[b+i]; mm = fmaxf(mm, logits[(size_t)e*4+h]); }
  float s = 0.f;
  for (int i=0;i<n;++i){ int e = csr[b+i]; s += __expf(logits[(size_t)e*4+h] - mm); }
  m[id] = mm;
  iden[id] = (n>0) ? 1.0f/s : 0.f;
}

// ============ edge value pass A: 2 edges per group, shared weight reads =====
// Writes 88 floats/edge into the first 88 floats of each stride-160 wflat row:
//   [0:32) vsg  [32:80) vvg(gated)  [80:84) alpha  [84:88) y
#define CA_RBF  0      // [112][20]
#define CA_VALS 2240   // [32][52]
#define CA_VVA  3904   // [16][36]
#define CA_VVB  4480   // [16][20]
#define CA_VVC  4800   // [16][20]
#define CA_G    5120   // [16][36]
#define CA_EDG  5696
#define CA_ESTR 400
// E: 0:s_[32] 32:v_[48] 80:r[16] 96:y[4] 100:a[4] 104:ms[48] 152:t_[32]
//    184:sa[16] 200:p[48] 248:q[48] 296:vs[32] 328:gv[16] 344:vv[48]

__global__ __launch_bounds__(256) void k_edgeCa(
    const int* __restrict__ csr, const int* __restrict__ ei,
    const float* __restrict__ rbf, const float* __restrict__ rsh,
    const float* __restrict__ Wrbf,
    const float* __restrict__ Wvals, const float* __restrict__ Wvalv,
    const float* __restrict__ Wg,
    const float* __restrict__ ss, const float* __restrict__ ds,
    const float* __restrict__ sv, const float* __restrict__ dv,
    const float* __restrict__ logits, const float* __restrict__ m,
    const float* __restrict__ iden, float* __restrict__ wflat)
{
  __shared__ __align__(16) float SH[CA_EDG + 16*CA_ESTR];
  const int t = threadIdx.x;
  for (int i=t; i<112*16; i+=256){ int d=i>>4, k=i&15; SH[CA_RBF+d*20+k]  = Wrbf[k*112+d]; }
  for (int i=t; i<32*48;  i+=256){ int d=i/48, k=i-48*d; SH[CA_VALS+d*52+k] = Wvals[k*32+d]; }
  for (int i=t; i<16*32;  i+=256){ int d=i>>5, k=i&31; SH[CA_VVA+d*36+k]  = Wvalv[k*16+d]; }
  for (int i=t; i<16*16;  i+=256){ int d=i>>4, k=i&15; SH[CA_VVB+d*20+k]  = Wvalv[(32+k)*16+d]; }
  for (int i=t; i<16*16;  i+=256){ int d=i>>4, k=i&15; SH[CA_VVC+d*20+k]  = Wvalv[(48+k)*16+d]; }
  for (int i=t; i<16*32;  i+=256){ int d=i>>5, k=i&31; SH[CA_G+d*36+k]    = Wg[k*16+d]; }
  __syncthreads();

  const int g = t >> 5;
  const int c = t & 31;
  float* E0 = &SH[CA_EDG + (2*g)*CA_ESTR];
  float* E1 = E0 + CA_ESTR;
  const float IS3 = 0.57735026918962576f;
  const float IS2 = 0.70710678118654752f;

#pragma unroll 1
  for (int tile=0; tile<8; ++tile){
    const int p0 = blockIdx.x*128 + tile*16 + 2*g;
    const int p1 = p0 + 1;
    const int ea = csr[p0], eb = csr[p1];
    const int sa = ei[ea], da = ei[EE + ea];
    const int sb = ei[eb], db = ei[EE + eb];

    // stage both edges
    if (c < 8){
      float4 a = *reinterpret_cast<const float4*>(ss + (size_t)sa*32 + c*4);
      float4 b = *reinterpret_cast<const float4*>(ds + (size_t)da*32 + c*4);
      float4 o; o.x=a.x+b.x; o.y=a.y+b.y; o.z=a.z+b.z; o.w=a.w+b.w;
      *reinterpret_cast<float4*>(&E0[c*4]) = o;
      float4 a2 = *reinterpret_cast<const float4*>(ss + (size_t)sb*32 + c*4);
      float4 b2 = *reinterpret_cast<const float4*>(ds + (size_t)db*32 + c*4);
      float4 o2; o2.x=a2.x+b2.x; o2.y=a2.y+b2.y; o2.z=a2.z+b2.z; o2.w=a2.w+b2.w;
      *reinterpret_cast<float4*>(&E1[c*4]) = o2;
    } else if (c < 20){
      int i = c-8;
      float4 a = *reinterpret_cast<const float4*>(sv + (size_t)sa*48 + i*4);
      float4 b = *reinterpret_cast<const float4*>(dv + (size_t)da*48 + i*4);
      float4 o; o.x=a.x+b.x; o.y=a.y+b.y; o.z=a.z+b.z; o.w=a.w+b.w;
      *reinterpret_cast<float4*>(&E0[32+i*4]) = o;
      float4 a2 = *reinterpret_cast<const float4*>(sv + (size_t)sb*48 + i*4);
      float4 b2 = *reinterpret_cast<const float4*>(dv + (size_t)db*48 + i*4);
      float4 o2; o2.x=a2.x+b2.x; o2.y=a2.y+b2.y; o2.z=a2.z+b2.z; o2.w=a2.w+b2.w;
      *reinterpret_cast<float4*>(&E1[32+i*4]) = o2;
    } else if (c < 24){
      int i = c-20;
      *reinterpret_cast<float4*>(&E0[80+i*4]) =
          *reinterpret_cast<const float4*>(rbf + (size_t)ea*16 + i*4);
      *reinterpret_cast<float4*>(&E1[80+i*4]) =
          *reinterpret_cast<const float4*>(rbf + (size_t)eb*16 + i*4);
    } else if (c == 24){
      *reinterpret_cast<float4*>(&E0[96]) =
          *reinterpret_cast<const float4*>(rsh + (size_t)ea*4);
      *reinterpret_cast<float4*>(&E1[96]) =
          *reinterpret_cast<const float4*>(rsh + (size_t)eb*4);
    } else if (c == 25){
      float4 l4 = *reinterpret_cast<const float4*>(logits + (size_t)ea*4);
      float4 m4 = *reinterpret_cast<const float4*>(m + (size_t)da*4);
      float4 i4 = *reinterpret_cast<const float4*>(iden + (size_t)da*4);
      E0[100] = __expf(l4.x-m4.x)*i4.x;
      E0[101] = __expf(l4.y-m4.y)*i4.y;
      E0[102] = __expf(l4.z-m4.z)*i4.z;
      E0[103] = __expf(l4.w-m4.w)*i4.w;
      float4 l5 = *reinterpret_cast<const float4*>(logits + (size_t)eb*4);
      float4 m5 = *reinterpret_cast<const float4*>(m + (size_t)db*4);
      float4 i5 = *reinterpret_cast<const float4*>(iden + (size_t)db*4);
      E1[100] = __expf(l5.x-m5.x)*i5.x;
      E1[101] = __expf(l5.y-m5.y)*i5.y;
      E1[102] = __expf(l5.z-m5.z)*i5.z;
      E1[103] = __expf(l5.w-m5.w)*i5.w;
    }

    // phase 1: w channels for both edges (weights read once)
    float rr0[16], rr1[16];
#pragma unroll
    for (int i=0;i<4;++i){
      *reinterpret_cast<float4*>(&rr0[i*4]) = *reinterpret_cast<const float4*>(&E0[80+i*4]);
      *reinterpret_cast<float4*>(&rr1[i*4]) = *reinterpret_cast<const float4*>(&E1[80+i*4]);
    }
    float wA0=0.f,wB0=0.f,wC0=0.f,wD0=0.f, wA1=0.f,wB1=0.f,wC1=0.f,wD1=0.f;
#pragma unroll
    for (int j4=0;j4<4;++j4){
      float4 a0 = *reinterpret_cast<const float4*>(&SH[CA_RBF + c*20           + j4*4]);
      float4 a1 = *reinterpret_cast<const float4*>(&SH[CA_RBF + (32+c)*20      + j4*4]);
      float4 a2 = *reinterpret_cast<const float4*>(&SH[CA_RBF + (64+c)*20      + j4*4]);
      float4 a3 = *reinterpret_cast<const float4*>(&SH[CA_RBF + (96+(c&15))*20 + j4*4]);
      float4 r0 = *reinterpret_cast<const float4*>(&rr0[j4*4]);
      float4 r1 = *reinterpret_cast<const float4*>(&rr1[j4*4]);
      wA0 += dot4(r0,a0); wA1 += dot4(r1,a0);
      wB0 += dot4(r0,a1); wB1 += dot4(r1,a1);
      wC0 += dot4(r0,a2); wC1 += dot4(r1,a2);
      wD0 += dot4(r0,a3); wD1 += dot4(r1,a3);
    }

    // phase 2: ms, t_, p, q (per edge, scalar)
    const float ya0=E0[96], yax=E0[97], yay=E0[98], yaz=E0[99];
    const float yb0=E1[96], ybx=E1[97], yby=E1[98], ybz=E1[99];
    const float sc0 = E0[c], sc1 = E1[c];
    E0[104+c] = wA0 * sc0 * ya0;   E1[104+c] = wA1 * sc1 * yb0;
    E0[152+c] = wB0 * sc0;         E1[152+c] = wB1 * sc1;
    if (c >= 16){
      int k = c-16;
      float vx=E0[32+k*3], vy=E0[33+k*3], vz=E0[34+k*3];
      E0[136+k] = wC0 * (vx*yax+vy*yay+vz*yaz) * IS3;
      float ux=E1[32+k*3], uy=E1[33+k*3], uz=E1[34+k*3];
      E1[136+k] = wC1 * (ux*ybx+uy*yby+uz*ybz) * IS3;
    }
    if (c < 16){
      int k = c;
      float vx=E0[32+k*3], vy=E0[33+k*3], vz=E0[34+k*3];
      float u0 = wC0 * ya0;
      E0[200+k]=u0*vx; E0[216+k]=u0*vy; E0[232+k]=u0*vz;
      float cx=(vy*yaz - vz*yay)*IS2;
      float cy=(vz*yax - vx*yaz)*IS2;
      float cz=(vx*yay - vy*yax)*IS2;
      E0[248+k]=wD0*cx; E0[264+k]=wD0*cy; E0[280+k]=wD0*cz;
      float ux=E1[32+k*3], uy=E1[33+k*3], uz=E1[34+k*3];
      float u1 = wC1 * yb0;
      E1[200+k]=u1*ux; E1[216+k]=u1*uy; E1[232+k]=u1*uz;
      float dx=(uy*ybz - uz*yby)*IS2;
      float dy=(uz*ybx - ux*ybz)*IS2;
      float dz=(ux*yby - uy*ybx)*IS2;
      E1[248+k]=wD1*dx; E1[264+k]=wD1*dy; E1[280+k]=wD1*dz;
    }

    // phase 3: sa[16] for both edges
    if (c < 16){
      float A0=0.f, A1=0.f;
#pragma unroll
      for (int k4=0;k4<8;++k4){
        float4 w = *reinterpret_cast<const float4*>(&SH[CA_VVA + c*36 + k4*4]);
        float4 t0 = *reinterpret_cast<const float4*>(&E0[152+k4*4]);
        float4 t1 = *reinterpret_cast<const float4*>(&E1[152+k4*4]);
        A0 += dot4(t0,w); A1 += dot4(t1,w);
      }
      E0[184+c]=A0; E1[184+c]=A1;
    }

    // phase 4: vv (ungated), both edges
    {
      int d0=c/3, x0=c-3*d0;
      float v00 = E0[184+d0]*E0[97+x0];
      float v10 = E1[184+d0]*E1[97+x0];
#pragma unroll
      for (int k4=0;k4<4;++k4){
        float4 wb = *reinterpret_cast<const float4*>(&SH[CA_VVB + d0*20 + k4*4]);
        float4 wc = *reinterpret_cast<const float4*>(&SH[CA_VVC + d0*20 + k4*4]);
        float4 pp0 = *reinterpret_cast<const float4*>(&E0[200 + x0*16 + k4*4]);
        float4 qq0 = *reinterpret_cast<const float4*>(&E0[248 + x0*16 + k4*4]);
        float4 pp1 = *reinterpret_cast<const float4*>(&E1[200 + x0*16 + k4*4]);
        float4 qq1 = *reinterpret_cast<const float4*>(&E1[248 + x0*16 + k4*4]);
        v00 += dot4(pp0,wb) + dot4(qq0,wc);
        v10 += dot4(pp1,wb) + dot4(qq1,wc);
      }
      E0[344+c]=v00; E1[344+c]=v10;
      if (c < 16){
        int l=32+c, d1=l/3, x1=l-3*d1;
        float v01 = E0[184+d1]*E0[97+x1];
        float v11 = E1[184+d1]*E1[97+x1];
#pragma unroll
        for (int k4=0;k4<4;++k4){
          float4 wb = *reinterpret_cast<const float4*>(&SH[CA_VVB + d1*20 + k4*4]);
          float4 wc = *reinterpret_cast<const float4*>(&SH[CA_VVC + d1*20 + k4*4]);
          float4 pp0 = *reinterpret_cast<const float4*>(&E0[200 + x1*16 + k4*4]);
          float4 qq0 = *reinterpret_cast<const float4*>(&E0[248 + x1*16 + k4*4]);
          float4 pp1 = *reinterpret_cast<const float4*>(&E1[200 + x1*16 + k4*4]);
          float4 qq1 = *reinterpret_cast<const float4*>(&E1[248 + x1*16 + k4*4]);
          v01 += dot4(pp0,wb) + dot4(qq0,wc);
          v11 += dot4(pp1,wb) + dot4(qq1,wc);
        }
        E0[344+l]=v01; E1[344+l]=v11;
      }
    }

    // phase 5: vs[32] both edges
    float av0=0.f, av1=0.f;
#pragma unroll
    for (int k4=0;k4<12;++k4){
      float4 w = *reinterpret_cast<const float4*>(&SH[CA_VALS + c*52 + k4*4]);
      float4 m0 = *reinterpret_cast<const float4*>(&E0[104+k4*4]);
      float4 m1 = *reinterpret_cast<const float4*>(&E1[104+k4*4]);
      av0 += dot4(m0,w); av1 += dot4(m1,w);
    }
    E0[296+c]=av0; E1[296+c]=av1;

    // phase 6: gv[16] both edges
    if (c < 16){
      float g0=0.f, g1=0.f;
#pragma unroll
      for (int k4=0;k4<8;++k4){
        float4 w = *reinterpret_cast<const float4*>(&SH[CA_G + c*36 + k4*4]);
        float4 v0 = *reinterpret_cast<const float4*>(&E0[296+k4*4]);
        float4 v1 = *reinterpret_cast<const float4*>(&E1[296+k4*4]);
        g0 += dot4(v0,w); g1 += dot4(v1,w);
      }
      E0[328+c]=sigm(g0); E1[328+c]=sigm(g1);
    }

    // phase 7: silu + gate, stream 88 floats per edge
    float* er0 = wflat + (size_t)p0*160;
    float* er1 = wflat + (size_t)p1*160;
    er0[c] = av0 * sigm(av0);
    er1[c] = av1 * sigm(av1);
    er0[32+c] = E0[344+c]*E0[328+c/3];
    er1[32+c] = E1[344+c]*E1[328+c/3];
    if (c < 16){
      int l = 32+c;
      er0[64+c] = E0[344+l]*E0[328+l/3];
      er1[64+c] = E1[344+l]*E1[328+l/3];
    }
    if (c < 8){
      er0[80+c] = (c<4) ? E0[100+c] : E0[96+c-4];
      er1[80+c] = (c<4) ? E1[100+c] : E1[96+c-4];
    }
  }
}

// ============ edge value pass, part B: second CG + projections (R5) ========
#define CB_VLS  0      // [64][52]
#define CB_VLVA 3328   // [32][36]
#define CB_VLVB 4480   // [32][20]
#define CB_VLVC 5120   // [32][20]
#define CB_W2   5760   // [112]
#define CB_EDG  5872
#define CB_ESTR 240
// E: 0:vvg[48] 48:a[4] 52:y[4] 56:vs2[48] 104:t2[32]
//    136:p2x[16] 152:p2y 168:p2z 184:q2x 200:q2y 216:q2z

__global__ __launch_bounds__(256) void k_edgeCb(
    const float* __restrict__ Wvls, const float* __restrict__ Wvlv,
    const float* __restrict__ w2, float* __restrict__ wflat)
{
  __shared__ __align__(16) float SH[CB_EDG + 8*CB_ESTR];
  const int t = threadIdx.x;
  for (int i=t; i<64*48; i+=256){ int d=i/48, k=i-48*d; SH[CB_VLS+d*52+k] = Wvls[k*64+d]; }
  for (int i=t; i<32*32; i+=256){ int d=i>>5, k=i&31; SH[CB_VLVA+d*36+k] = Wvlv[k*32+d]; }
  for (int i=t; i<32*16; i+=256){ int d=i>>4, k=i&15; SH[CB_VLVB+d*20+k] = Wvlv[(32+k)*32+d]; }
  for (int i=t; i<32*16; i+=256){ int d=i>>4, k=i&15; SH[CB_VLVC+d*20+k] = Wvlv[(48+k)*32+d]; }
  for (int i=t; i<112;   i+=256){ SH[CB_W2+i] = w2[i]; }
  __syncthreads();

  const int g = t >> 5;
  const int c = t & 31;
  float* E = &SH[CB_EDG + g*CB_ESTR];
  const float IS3 = 0.57735026918962576f;
  const float IS2 = 0.70710678118654752f;

#pragma unroll 1
  for (int tile=0; tile<16; ++tile){
    const int pidx = blockIdx.x*128 + tile*8 + g;
    float* wrow = wflat + (size_t)pidx*160;

    const float vsc = wrow[c];
    E[c] = wrow[32+c];
    if (c < 16) E[32+c] = wrow[64+c];
    if (c < 8)  E[48+c] = wrow[80+c];

    const float y0=E[52], y1x=E[53], y1y=E[54], y1z=E[55];

    E[104+c] = SH[CB_W2+32+c]*vsc;
    E[56+c]  = SH[CB_W2+c]*vsc*y0;
    if (c >= 16){
      int k = c-16;
      float gx=E[k*3], gy=E[k*3+1], gz=E[k*3+2];
      E[88+k] = SH[CB_W2+80+k]*(gx*y1x+gy*y1y+gz*y1z)*IS3;
    }
    if (c < 16){
      int k = c;
      float gx=E[k*3], gy=E[k*3+1], gz=E[k*3+2];
      float u = SH[CB_W2+64+k]*y0;
      E[136+k]=u*gx; E[152+k]=u*gy; E[168+k]=u*gz;
      float cx=(gy*y1z - gz*y1y)*IS2;
      float cy=(gz*y1x - gx*y1z)*IS2;
      float cz=(gx*y1y - gy*y1x)*IS2;
      float wq = SH[CB_W2+96+k];
      E[184+k]=wq*cx; E[200+k]=wq*cy; E[216+k]=wq*cz;
    }

    const float a0=E[48], a1=E[49], a2h=E[50], a3h=E[51];

    {
      float f0a=0.f, f0b=0.f, f1a=0.f, f1b=0.f;
#pragma unroll
      for (int k4=0;k4<12;k4+=2){
        float4 v0 = *reinterpret_cast<const float4*>(&E[56+k4*4]);
        float4 v1 = *reinterpret_cast<const float4*>(&E[56+k4*4+4]);
        float4 wa0 = *reinterpret_cast<const float4*>(&SH[CB_VLS + c*52 + k4*4]);
        float4 wa1 = *reinterpret_cast<const float4*>(&SH[CB_VLS + c*52 + k4*4+4]);
        float4 wb0 = *reinterpret_cast<const float4*>(&SH[CB_VLS + (32+c)*52 + k4*4]);
        float4 wb1 = *reinterpret_cast<const float4*>(&SH[CB_VLS + (32+c)*52 + k4*4+4]);
        f0a += dot4(v0,wa0); f0b += dot4(v1,wa1);
        f1a += dot4(v0,wb0); f1b += dot4(v1,wb1);
      }
      wrow[c]    = (f0a+f0b)*a0;
      wrow[32+c] = (f1a+f1b)*((c<8)?a0:a1);
    }

    {
      float A2=0.f, A2b=0.f;
#pragma unroll
      for (int k4=0;k4<8;k4+=2){
        float4 w0 = *reinterpret_cast<const float4*>(&SH[CB_VLVA + c*36 + k4*4]);
        float4 t0 = *reinterpret_cast<const float4*>(&E[104+k4*4]);
        float4 w1 = *reinterpret_cast<const float4*>(&SH[CB_VLVA + c*36 + k4*4+4]);
        float4 t1 = *reinterpret_cast<const float4*>(&E[104+k4*4+4]);
        A2  += dot4(t0,w0); A2b += dot4(t1,w1);
      }
      A2 += A2b;
      float b0=A2*y1x, b1=A2*y1y, b2=A2*y1z;
#pragma unroll
      for (int k4=0;k4<4;++k4){
        float4 wb = *reinterpret_cast<const float4*>(&SH[CB_VLVB + c*20 + k4*4]);
        float4 wc = *reinterpret_cast<const float4*>(&SH[CB_VLVC + c*20 + k4*4]);
        float4 p0 = *reinterpret_cast<const float4*>(&E[136 + k4*4]);
        float4 p1 = *reinterpret_cast<const float4*>(&E[152 + k4*4]);
        float4 p2v= *reinterpret_cast<const float4*>(&E[168 + k4*4]);
        float4 q0 = *reinterpret_cast<const float4*>(&E[184 + k4*4]);
        float4 q1 = *reinterpret_cast<const float4*>(&E[200 + k4*4]);
        float4 q2v= *reinterpret_cast<const float4*>(&E[216 + k4*4]);
        b0 += dot4(p0,wb) + dot4(q0,wc);
        b1 += dot4(p1,wb) + dot4(q1,wc);
        b2 += dot4(p2v,wb) + dot4(q2v,wc);
      }
      int o = 64 + c*3;
      float aw0 = (o   < 80) ? a1 : ((o   < 120) ? a2h : a3h);
      float aw1 = (o+1 < 80) ? a1 : ((o+1 < 120) ? a2h : a3h);
      float aw2 = (o+2 < 80) ? a1 : ((o+2 < 120) ? a2h : a3h);
      wrow[o]   = b0*aw0;
      wrow[o+1] = b1*aw1;
      wrow[o+2] = b2*aw2;
    }
  }
}

// ------------- gather: per-dst sum of weighted per-edge rows ---------------
__global__ __launch_bounds__(256) void k_gather(
    const int* __restrict__ base, const int* __restrict__ deg,
    const float* __restrict__ wflat, float* __restrict__ agg)
{
  int id = blockIdx.x*256 + threadIdx.x;
  if (id >= NN*40) return;
  int d = id / 40, c = id % 40;
  int b = base[d], n = deg[d];
  float4 acc = make_float4(0.f,0.f,0.f,0.f);
  for (int i=0;i<n;++i){
    float4 w = reinterpret_cast<const float4*>(wflat + (size_t)(b+i)*160)[c];
    acc.x += w.x; acc.y += w.y; acc.z += w.z; acc.w += w.w;
  }
  reinterpret_cast<float4*>(agg + (size_t)d*160)[c] = acc;
}

// ------------- output pass: Wp projections + residual ----------------------
__global__ __launch_bounds__(256) void k_out(
    const float* __restrict__ node, const float* __restrict__ agg,
    const float* __restrict__ Wps, const float* __restrict__ Wpv,
    float* __restrict__ out)
{
  int n = blockIdx.x * 256 + threadIdx.x;
  if (n >= NN) return;
  const float* ar = agg + (size_t)n*160;
  const float* nr = node + (size_t)n*80;
  float* orow = out + (size_t)n*80;

  float a[64];
  { const float4* ap = reinterpret_cast<const float4*>(ar);
#pragma unroll
    for (int i=0;i<16;++i){ float4 t=ap[i];
      a[i*4]=t.x; a[i*4+1]=t.y; a[i*4+2]=t.z; a[i*4+3]=t.w; } }
#pragma unroll 1
  for (int d=0; d<32; ++d){
    float acc=0.f;
#pragma unroll
    for (int c=0;c<64;++c) acc += a[c]*Wps[c*32+d];
    orow[d] = nr[d] + acc;
  }
  float b[96];
  { const float4* bp = reinterpret_cast<const float4*>(ar + 64);
#pragma unroll
    for (int i=0;i<24;++i){ float4 t=bp[i];
      b[i*4]=t.x; b[i*4+1]=t.y; b[i*4+2]=t.z; b[i*4+3]=t.w; } }
#pragma unroll 1
  for (int d=0; d<16; ++d){
#pragma unroll
    for (int x=0;x<3;++x){
      float acc=0.f;
#pragma unroll
      for (int c=0;c<32;++c) acc += b[c*3+x]*Wpv[c*16+d];
      orow[32+d*3+x] = nr[32+d*3+x] + acc;
    }
  }
}

extern "C" void kernel_launch(void* const* d_in, const int* in_sizes, int n_in,
                              void* d_out, int out_size, void* d_ws, size_t ws_size,
                              hipStream_t stream)
{
  const float* node   = (const float*)d_in[0];
  const float* rbf    = (const float*)d_in[1];
  const float* rsh    = (const float*)d_in[2];
  const float* Wsrc_s = (const float*)d_in[3];
  const float* Wsrc_v = (const float*)d_in[4];
  const float* Wdst_s = (const float*)d_in[5];
  const float* Wdst_v = (const float*)d_in[6];
  const float* W_rbf  = (const float*)d_in[7];
  const float* dtp2   = (const float*)d_in[8];
  const float* Wa     = (const float*)d_in[9];
  const float* adot   = (const float*)d_in[10];
  const float* Wval_s = (const float*)d_in[11];
  const float* Wval_v = (const float*)d_in[12];
  const float* Wg     = (const float*)d_in[13];
  const float* Wvl_s  = (const float*)d_in[14];
  const float* Wvl_v  = (const float*)d_in[15];
  const float* Wp_s   = (const float*)d_in[16];
  const float* Wp_v   = (const float*)d_in[17];
  const int*   ei     = (const int*)d_in[18];

  float* ws = (float*)d_ws;

  size_t off = 0;
  float* ss   = ws + off; off += (size_t)NN*32;
  float* ds   = ws + off; off += (size_t)NN*32;
  float* sv   = ws + off; off += (size_t)NN*48;
  float* dv   = ws + off; off += (size_t)NN*48;
  float* lg   = ws + off; off += (size_t)EE*4;
  float* m    = ws + off; off += (size_t)NN*4;
  float* iden = ws + off; off += (size_t)NN*4;
  int* deg    = (int*)(ws + off); off += (size_t)NN;
  int* base   = (int*)(ws + off); off += (size_t)NN;
  int* cursor = (int*)(ws + off); off += (size_t)NN;
  int* csr    = (int*)(ws + off); off += (size_t)EE;
  float* agg  = ws + off; off += (size_t)NN*160;
  float* wflat= ws + off; off += (size_t)EE*160;
  size_t need_new = off * sizeof(float);
  if (ws_size < need_new) return;

  hipMemsetAsync(deg, 0, (size_t)NN*sizeof(int), stream);
  k_node   <<<NN/256, 256, 0, stream>>>(node, Wsrc_s, Wsrc_v, Wdst_s, Wdst_v, ss, ds, sv, dv);
  k_hist   <<<EE/256, 256, 0, stream>>>(ei, deg);
  k_scan   <<<1, 1024, 0, stream>>>(deg, base, cursor);
  k_scatter<<<EE/256, 256, 0, stream>>>(ei, cursor, csr);
  k_edgeA2 <<<EE/256, 512, 0, stream>>>(ei, rbf, rsh, W_rbf, Wa, adot, ss, ds, sv, dv, lg);
  k_soft   <<<(NN*4)/256, 256, 0, stream>>>(base, deg, csr, lg, m, iden);
  k_edgeCa <<<EE/128, 256, 0, stream>>>(csr, ei, rbf, rsh, W_rbf, Wval_s, Wval_v, Wg,
                                        ss, ds, sv, dv, lg, m, iden, wflat);
  k_edgeCb <<<EE/128, 256, 0, stream>>>(Wvl_s, Wvl_v, dtp2, wflat);
  k_gather <<<(NN*40)/256, 256, 0, stream>>>(base, deg, wflat, agg);
  k_out    <<<NN/256, 256, 0, stream>>>(node, agg, Wp_s, Wp_v, (float*)d_out);
}

// Round 9
// 521.650 us; speedup vs baseline: 1.2590x; 1.0285x over previous
//
#include <hip/hip_runtime.h>

#define NN 32768
#define EE 262144

static __device__ __forceinline__ float sigm(float x){
  return 1.0f / (1.0f + __expf(-x));
}
static __device__ __forceinline__ float dot4(float4 a, float4 b){
  return a.x*b.x + a.y*b.y + a.z*b.z + a.w*b.w;
}

// ---------------- node pass: o3-layernorm + src/dst linears ----------------
__global__ __launch_bounds__(256) void k_node(
    const float* __restrict__ node,
    const float* __restrict__ Wss, const float* __restrict__ Wsv,
    const float* __restrict__ Wds, const float* __restrict__ Wdv,
    float* __restrict__ ss, float* __restrict__ ds,
    float* __restrict__ sv, float* __restrict__ dv)
{
  int n = blockIdx.x * 256 + threadIdx.x;
  if (n >= NN) return;
  const float4* row = reinterpret_cast<const float4*>(node + (size_t)n * 80);
  float s[32], v[48];
#pragma unroll
  for (int i = 0; i < 8; ++i){
    float4 t = row[i];
    s[i*4+0]=t.x; s[i*4+1]=t.y; s[i*4+2]=t.z; s[i*4+3]=t.w;
  }
#pragma unroll
  for (int i = 0; i < 12; ++i){
    float4 t = row[8+i];
    v[i*4+0]=t.x; v[i*4+1]=t.y; v[i*4+2]=t.z; v[i*4+3]=t.w;
  }
  float mean = 0.f;
#pragma unroll
  for (int i=0;i<32;++i) mean += s[i];
  mean *= (1.0f/32.0f);
  float var = 0.f;
#pragma unroll
  for (int i=0;i<32;++i){ float d0 = s[i]-mean; var += d0*d0; }
  var *= (1.0f/32.0f);
  float sinv = rsqrtf(var + 1e-5f);
#pragma unroll
  for (int i=0;i<32;++i) s[i] = (s[i]-mean)*sinv;
  float n2 = 0.f;
#pragma unroll
  for (int i=0;i<48;++i) n2 += v[i]*v[i];
  n2 *= (1.0f/16.0f);
  float vinv = rsqrtf(n2 + 1e-5f);
#pragma unroll
  for (int i=0;i<48;++i) v[i] *= vinv;

  float* ssr = ss + (size_t)n*32;
  float* dsr = ds + (size_t)n*32;
#pragma unroll 1
  for (int d=0; d<32; ++d){
    float a=0.f, b=0.f;
#pragma unroll
    for (int c=0;c<32;++c){ a += s[c]*Wss[c*32+d]; b += s[c]*Wds[c*32+d]; }
    ssr[d]=a; dsr[d]=b;
  }
  float* svr = sv + (size_t)n*48;
  float* dvr = dv + (size_t)n*48;
#pragma unroll 1
  for (int d=0; d<16; ++d){
#pragma unroll
    for (int x=0;x<3;++x){
      float a=0.f, b=0.f;
#pragma unroll
      for (int c=0;c<16;++c){ a += v[c*3+x]*Wsv[c*16+d]; b += v[c*3+x]*Wdv[c*16+d]; }
      svr[d*3+x]=a; dvr[d*3+x]=b;
    }
  }
}

// ---------------- CSR build ----------------
__global__ __launch_bounds__(256) void k_hist(const int* __restrict__ ei, int* __restrict__ deg){
  int e = blockIdx.x*256 + threadIdx.x;
  if (e >= EE) return;
  atomicAdd(deg + ei[EE + e], 1);
}

__global__ __launch_bounds__(1024) void k_scan(const int* __restrict__ deg,
                                               int* __restrict__ base, int* __restrict__ cursor){
  __shared__ int lds[1024];
  int t = threadIdx.x;
  int v[32];
#pragma unroll
  for (int i=0;i<32;++i) v[i] = deg[t*32+i];
  int run = 0;
#pragma unroll
  for (int i=0;i<32;++i){ int x=v[i]; v[i]=run; run+=x; }
  lds[t]=run; __syncthreads();
  for (int off=1; off<1024; off<<=1){
    int add = (t>=off) ? lds[t-off] : 0;
    __syncthreads();
    lds[t] += add;
    __syncthreads();
  }
  int pre = (t==0) ? 0 : lds[t-1];
#pragma unroll
  for (int i=0;i<32;++i){ int b = pre + v[i]; base[t*32+i]=b; cursor[t*32+i]=b; }
}

__global__ __launch_bounds__(256) void k_scatter(const int* __restrict__ ei,
                                                 int* __restrict__ cursor, int* __restrict__ csr){
  int e = blockIdx.x*256 + threadIdx.x;
  if (e >= EE) return;
  int d = ei[EE + e];
  int pos = atomicAdd(cursor + d, 1);
  csr[pos] = e;
}

// ============== cooperative edge pass A: 2 edges per 32-lane group =========
#define A_RBFA 0      // [32][20]
#define A_RBFD 640    // [16][20]
#define A_WA   960    // [64][52]
#define A_ADOT 4288
#define A_EDG  4352
#define A_ESTR 152
// E: 0:s_[32] 32:v_[48] 80:r[16] 96:y[4] 104:ms[48]

__global__ __launch_bounds__(512) void k_edgeA2(
    const int* __restrict__ ei,
    const float* __restrict__ rbf, const float* __restrict__ rsh,
    const float* __restrict__ Wrbf, const float* __restrict__ Wa,
    const float* __restrict__ adot,
    const float* __restrict__ ss, const float* __restrict__ ds,
    const float* __restrict__ sv, const float* __restrict__ dv,
    float* __restrict__ logits)
{
  __shared__ __align__(16) float SH[A_EDG + 32*A_ESTR];
  const int t = threadIdx.x;
  for (int i=t; i<32*16; i+=512){ int row=i>>4, j=i&15; SH[A_RBFA+row*20+j] = Wrbf[j*112+row]; }
  for (int i=t; i<16*16; i+=512){ int row=i>>4, j=i&15; SH[A_RBFD+row*20+j] = Wrbf[j*112+80+row]; }
  for (int i=t; i<64*48; i+=512){ int o=i/48, k=i-48*o; SH[A_WA+o*52+k] = Wa[k*64+o]; }
  for (int i=t; i<64;    i+=512){ SH[A_ADOT+i] = adot[i]; }
  __syncthreads();

  const int g = t >> 5;
  const int c = t & 31;
  float* E0 = &SH[A_EDG + (2*g)*A_ESTR];
  float* E1 = E0 + A_ESTR;
  const float IS3 = 0.57735026918962576f;

#pragma unroll 1
  for (int tile=0; tile<8; ++tile){
    const int e0 = blockIdx.x*256 + tile*32 + 2*g;
    const int e1 = e0 + 1;
    const int s0i = ei[e0], d0i = ei[EE + e0];
    const int s1i = ei[e1], d1i = ei[EE + e1];

    if (c < 8){
      float4 a = *reinterpret_cast<const float4*>(ss + (size_t)s0i*32 + c*4);
      float4 b = *reinterpret_cast<const float4*>(ds + (size_t)d0i*32 + c*4);
      float4 o; o.x=a.x+b.x; o.y=a.y+b.y; o.z=a.z+b.z; o.w=a.w+b.w;
      *reinterpret_cast<float4*>(&E0[c*4]) = o;
      float4 a2 = *reinterpret_cast<const float4*>(ss + (size_t)s1i*32 + c*4);
      float4 b2 = *reinterpret_cast<const float4*>(ds + (size_t)d1i*32 + c*4);
      float4 o2; o2.x=a2.x+b2.x; o2.y=a2.y+b2.y; o2.z=a2.z+b2.z; o2.w=a2.w+b2.w;
      *reinterpret_cast<float4*>(&E1[c*4]) = o2;
    } else if (c < 20){
      int i = c-8;
      float4 a = *reinterpret_cast<const float4*>(sv + (size_t)s0i*48 + i*4);
      float4 b = *reinterpret_cast<const float4*>(dv + (size_t)d0i*48 + i*4);
      float4 o; o.x=a.x+b.x; o.y=a.y+b.y; o.z=a.z+b.z; o.w=a.w+b.w;
      *reinterpret_cast<float4*>(&E0[32+i*4]) = o;
      float4 a2 = *reinterpret_cast<const float4*>(sv + (size_t)s1i*48 + i*4);
      float4 b2 = *reinterpret_cast<const float4*>(dv + (size_t)d1i*48 + i*4);
      float4 o2; o2.x=a2.x+b2.x; o2.y=a2.y+b2.y; o2.z=a2.z+b2.z; o2.w=a2.w+b2.w;
      *reinterpret_cast<float4*>(&E1[32+i*4]) = o2;
    } else if (c < 24){
      int i = c-20;
      *reinterpret_cast<float4*>(&E0[80+i*4]) =
          *reinterpret_cast<const float4*>(rbf + (size_t)e0*16 + i*4);
      *reinterpret_cast<float4*>(&E1[80+i*4]) =
          *reinterpret_cast<const float4*>(rbf + (size_t)e1*16 + i*4);
    } else if (c == 24){
      *reinterpret_cast<float4*>(&E0[96]) =
          *reinterpret_cast<const float4*>(rsh + (size_t)e0*4);
      *reinterpret_cast<float4*>(&E1[96]) =
          *reinterpret_cast<const float4*>(rsh + (size_t)e1*4);
    }

    float rr0[16], rr1[16];
#pragma unroll
    for (int i=0;i<4;++i){
      *reinterpret_cast<float4*>(&rr0[i*4]) = *reinterpret_cast<const float4*>(&E0[80+i*4]);
      *reinterpret_cast<float4*>(&rr1[i*4]) = *reinterpret_cast<const float4*>(&E1[80+i*4]);
    }
    const float ya0=E0[96], yax=E0[97], yay=E0[98], yaz=E0[99];
    const float yb0=E1[96], ybx=E1[97], yby=E1[98], ybz=E1[99];
    {
      float wA0=0.f, wA1=0.f;
#pragma unroll
      for (int j4=0;j4<4;++j4){
        float4 w = *reinterpret_cast<const float4*>(&SH[A_RBFA + c*20 + j4*4]);
        float4 r0 = *reinterpret_cast<const float4*>(&rr0[j4*4]);
        float4 r1 = *reinterpret_cast<const float4*>(&rr1[j4*4]);
        wA0 += dot4(r0,w); wA1 += dot4(r1,w);
      }
      E0[104+c] = wA0 * E0[c] * ya0;
      E1[104+c] = wA1 * E1[c] * yb0;
    }
    if (c < 16){
      float wD0=0.f, wD1=0.f;
#pragma unroll
      for (int j4=0;j4<4;++j4){
        float4 w = *reinterpret_cast<const float4*>(&SH[A_RBFD + c*20 + j4*4]);
        float4 r0 = *reinterpret_cast<const float4*>(&rr0[j4*4]);
        float4 r1 = *reinterpret_cast<const float4*>(&rr1[j4*4]);
        wD0 += dot4(r0,w); wD1 += dot4(r1,w);
      }
      float vx=E0[32+c*3], vy=E0[33+c*3], vz=E0[34+c*3];
      E0[136+c] = wD0 * (vx*yax + vy*yay + vz*yaz) * IS3;
      float ux=E1[32+c*3], uy=E1[33+c*3], uz=E1[34+c*3];
      E1[136+c] = wD1 * (ux*ybx + uy*yby + uz*ybz) * IS3;
    }

    float a00=0.f, a01=0.f, a10=0.f, a11=0.f;
#pragma unroll
    for (int k4=0;k4<12;++k4){
      float4 w0 = *reinterpret_cast<const float4*>(&SH[A_WA + c*52 + k4*4]);
      float4 w1 = *reinterpret_cast<const float4*>(&SH[A_WA + (32+c)*52 + k4*4]);
      float4 m0 = *reinterpret_cast<const float4*>(&E0[104+k4*4]);
      float4 m1 = *reinterpret_cast<const float4*>(&E1[104+k4*4]);
      a00 += dot4(m0,w0); a01 += dot4(m0,w1);
      a10 += dot4(m1,w0); a11 += dot4(m1,w1);
    }
    const float ad0 = SH[A_ADOT+c], ad1 = SH[A_ADOT+32+c];
    a00 = ((a00 > 0.f) ? a00 : 0.2f*a00) * ad0;
    a01 = ((a01 > 0.f) ? a01 : 0.2f*a01) * ad1;
    a10 = ((a10 > 0.f) ? a10 : 0.2f*a10) * ad0;
    a11 = ((a11 > 0.f) ? a11 : 0.2f*a11) * ad1;
#pragma unroll
    for (int msk=8; msk>=1; msk>>=1){
      a00 += __shfl_xor(a00, msk);
      a01 += __shfl_xor(a01, msk);
      a10 += __shfl_xor(a10, msk);
      a11 += __shfl_xor(a11, msk);
    }
    if ((c & 15) == 0){
      int h0 = c >> 4;
      logits[(size_t)e0*4 + h0]     = a00;
      logits[(size_t)e0*4 + 2 + h0] = a01;
      logits[(size_t)e1*4 + h0]     = a10;
      logits[(size_t)e1*4 + 2 + h0] = a11;
    }
  }
}

// ------------- per-(dst,head) softmax stats via CSR (no atomics) ----------
__global__ __launch_bounds__(256) void k_soft(
    const int* __restrict__ base, const int* __restrict__ deg,
    const int* __restrict__ csr, const float* __restrict__ logits,
    float* __restrict__ m, float* __restrict__ iden)
{
  int id = blockIdx.x*256 + threadIdx.x;
  if (id >= NN*4) return;
  int d = id >> 2, h = id & 3;
  int b = base[d], n = deg[d];
  float mm = -3.4e38f;
  for (int i=0;i<n;++i){ int e = csr[b+i]; mm = fmaxf(mm, logits[(size_t)e*4+h]); }
  float s = 0.f;
  for (int i=0;i<n;++i){ int e = csr[b+i]; s += __expf(logits[(size_t)e*4+h] - mm); }
  m[id] = mm;
  iden[id] = (n>0) ? 1.0f/s : 0.f;
}

// ============ edge value pass A: 2 edges per group, shared weight reads =====
#define CA_RBF  0      // [112][20]
#define CA_VALS 2240   // [32][52]
#define CA_VVA  3904   // [16][36]
#define CA_VVB  4480   // [16][20]
#define CA_VVC  4800   // [16][20]
#define CA_G    5120   // [16][36]
#define CA_EDG  5696
#define CA_ESTR 400

__global__ __launch_bounds__(256) void k_edgeCa(
    const int* __restrict__ csr, const int* __restrict__ ei,
    const float* __restrict__ rbf, const float* __restrict__ rsh,
    const float* __restrict__ Wrbf,
    const float* __restrict__ Wvals, const float* __restrict__ Wvalv,
    const float* __restrict__ Wg,
    const float* __restrict__ ss, const float* __restrict__ ds,
    const float* __restrict__ sv, const float* __restrict__ dv,
    const float* __restrict__ logits, const float* __restrict__ m,
    const float* __restrict__ iden, float* __restrict__ wflat)
{
  __shared__ __align__(16) float SH[CA_EDG + 16*CA_ESTR];
  const int t = threadIdx.x;
  for (int i=t; i<112*16; i+=256){ int d=i>>4, k=i&15; SH[CA_RBF+d*20+k]  = Wrbf[k*112+d]; }
  for (int i=t; i<32*48;  i+=256){ int d=i/48, k=i-48*d; SH[CA_VALS+d*52+k] = Wvals[k*32+d]; }
  for (int i=t; i<16*32;  i+=256){ int d=i>>5, k=i&31; SH[CA_VVA+d*36+k]  = Wvalv[k*16+d]; }
  for (int i=t; i<16*16;  i+=256){ int d=i>>4, k=i&15; SH[CA_VVB+d*20+k]  = Wvalv[(32+k)*16+d]; }
  for (int i=t; i<16*16;  i+=256){ int d=i>>4, k=i&15; SH[CA_VVC+d*20+k]  = Wvalv[(48+k)*16+d]; }
  for (int i=t; i<16*32;  i+=256){ int d=i>>5, k=i&31; SH[CA_G+d*36+k]    = Wg[k*16+d]; }
  __syncthreads();

  const int g = t >> 5;
  const int c = t & 31;
  float* E0 = &SH[CA_EDG + (2*g)*CA_ESTR];
  float* E1 = E0 + CA_ESTR;
  const float IS3 = 0.57735026918962576f;
  const float IS2 = 0.70710678118654752f;

#pragma unroll 1
  for (int tile=0; tile<8; ++tile){
    const int p0 = blockIdx.x*128 + tile*16 + 2*g;
    const int p1 = p0 + 1;
    const int ea = csr[p0], eb = csr[p1];
    const int sa = ei[ea], da = ei[EE + ea];
    const int sb = ei[eb], db = ei[EE + eb];

    if (c < 8){
      float4 a = *reinterpret_cast<const float4*>(ss + (size_t)sa*32 + c*4);
      float4 b = *reinterpret_cast<const float4*>(ds + (size_t)da*32 + c*4);
      float4 o; o.x=a.x+b.x; o.y=a.y+b.y; o.z=a.z+b.z; o.w=a.w+b.w;
      *reinterpret_cast<float4*>(&E0[c*4]) = o;
      float4 a2 = *reinterpret_cast<const float4*>(ss + (size_t)sb*32 + c*4);
      float4 b2 = *reinterpret_cast<const float4*>(ds + (size_t)db*32 + c*4);
      float4 o2; o2.x=a2.x+b2.x; o2.y=a2.y+b2.y; o2.z=a2.z+b2.z; o2.w=a2.w+b2.w;
      *reinterpret_cast<float4*>(&E1[c*4]) = o2;
    } else if (c < 20){
      int i = c-8;
      float4 a = *reinterpret_cast<const float4*>(sv + (size_t)sa*48 + i*4);
      float4 b = *reinterpret_cast<const float4*>(dv + (size_t)da*48 + i*4);
      float4 o; o.x=a.x+b.x; o.y=a.y+b.y; o.z=a.z+b.z; o.w=a.w+b.w;
      *reinterpret_cast<float4*>(&E0[32+i*4]) = o;
      float4 a2 = *reinterpret_cast<const float4*>(sv + (size_t)sb*48 + i*4);
      float4 b2 = *reinterpret_cast<const float4*>(dv + (size_t)db*48 + i*4);
      float4 o2; o2.x=a2.x+b2.x; o2.y=a2.y+b2.y; o2.z=a2.z+b2.z; o2.w=a2.w+b2.w;
      *reinterpret_cast<float4*>(&E1[32+i*4]) = o2;
    } else if (c < 24){
      int i = c-20;
      *reinterpret_cast<float4*>(&E0[80+i*4]) =
          *reinterpret_cast<const float4*>(rbf + (size_t)ea*16 + i*4);
      *reinterpret_cast<float4*>(&E1[80+i*4]) =
          *reinterpret_cast<const float4*>(rbf + (size_t)eb*16 + i*4);
    } else if (c == 24){
      *reinterpret_cast<float4*>(&E0[96]) =
          *reinterpret_cast<const float4*>(rsh + (size_t)ea*4);
      *reinterpret_cast<float4*>(&E1[96]) =
          *reinterpret_cast<const float4*>(rsh + (size_t)eb*4);
    } else if (c == 25){
      float4 l4 = *reinterpret_cast<const float4*>(logits + (size_t)ea*4);
      float4 m4 = *reinterpret_cast<const float4*>(m + (size_t)da*4);
      float4 i4 = *reinterpret_cast<const float4*>(iden + (size_t)da*4);
      E0[100] = __expf(l4.x-m4.x)*i4.x;
      E0[101] = __expf(l4.y-m4.y)*i4.y;
      E0[102] = __expf(l4.z-m4.z)*i4.z;
      E0[103] = __expf(l4.w-m4.w)*i4.w;
      float4 l5 = *reinterpret_cast<const float4*>(logits + (size_t)eb*4);
      float4 m5 = *reinterpret_cast<const float4*>(m + (size_t)db*4);
      float4 i5 = *reinterpret_cast<const float4*>(iden + (size_t)db*4);
      E1[100] = __expf(l5.x-m5.x)*i5.x;
      E1[101] = __expf(l5.y-m5.y)*i5.y;
      E1[102] = __expf(l5.z-m5.z)*i5.z;
      E1[103] = __expf(l5.w-m5.w)*i5.w;
    }

    float rr0[16], rr1[16];
#pragma unroll
    for (int i=0;i<4;++i){
      *reinterpret_cast<float4*>(&rr0[i*4]) = *reinterpret_cast<const float4*>(&E0[80+i*4]);
      *reinterpret_cast<float4*>(&rr1[i*4]) = *reinterpret_cast<const float4*>(&E1[80+i*4]);
    }
    float wA0=0.f,wB0=0.f,wC0=0.f,wD0=0.f, wA1=0.f,wB1=0.f,wC1=0.f,wD1=0.f;
#pragma unroll
    for (int j4=0;j4<4;++j4){
      float4 a0 = *reinterpret_cast<const float4*>(&SH[CA_RBF + c*20           + j4*4]);
      float4 a1 = *reinterpret_cast<const float4*>(&SH[CA_RBF + (32+c)*20      + j4*4]);
      float4 a2 = *reinterpret_cast<const float4*>(&SH[CA_RBF + (64+c)*20      + j4*4]);
      float4 a3 = *reinterpret_cast<const float4*>(&SH[CA_RBF + (96+(c&15))*20 + j4*4]);
      float4 r0 = *reinterpret_cast<const float4*>(&rr0[j4*4]);
      float4 r1 = *reinterpret_cast<const float4*>(&rr1[j4*4]);
      wA0 += dot4(r0,a0); wA1 += dot4(r1,a0);
      wB0 += dot4(r0,a1); wB1 += dot4(r1,a1);
      wC0 += dot4(r0,a2); wC1 += dot4(r1,a2);
      wD0 += dot4(r0,a3); wD1 += dot4(r1,a3);
    }

    const float ya0=E0[96], yax=E0[97], yay=E0[98], yaz=E0[99];
    const float yb0=E1[96], ybx=E1[97], yby=E1[98], ybz=E1[99];
    const float sc0 = E0[c], sc1 = E1[c];
    E0[104+c] = wA0 * sc0 * ya0;   E1[104+c] = wA1 * sc1 * yb0;
    E0[152+c] = wB0 * sc0;         E1[152+c] = wB1 * sc1;
    if (c >= 16){
      int k = c-16;
      float vx=E0[32+k*3], vy=E0[33+k*3], vz=E0[34+k*3];
      E0[136+k] = wC0 * (vx*yax+vy*yay+vz*yaz) * IS3;
      float ux=E1[32+k*3], uy=E1[33+k*3], uz=E1[34+k*3];
      E1[136+k] = wC1 * (ux*ybx+uy*yby+uz*ybz) * IS3;
    }
    if (c < 16){
      int k = c;
      float vx=E0[32+k*3], vy=E0[33+k*3], vz=E0[34+k*3];
      float u0 = wC0 * ya0;
      E0[200+k]=u0*vx; E0[216+k]=u0*vy; E0[232+k]=u0*vz;
      float cx=(vy*yaz - vz*yay)*IS2;
      float cy=(vz*yax - vx*yaz)*IS2;
      float cz=(vx*yay - vy*yax)*IS2;
      E0[248+k]=wD0*cx; E0[264+k]=wD0*cy; E0[280+k]=wD0*cz;
      float ux=E1[32+k*3], uy=E1[33+k*3], uz=E1[34+k*3];
      float u1 = wC1 * yb0;
      E1[200+k]=u1*ux; E1[216+k]=u1*uy; E1[232+k]=u1*uz;
      float dx=(uy*ybz - uz*yby)*IS2;
      float dy=(uz*ybx - ux*ybz)*IS2;
      float dz=(ux*yby - uy*ybx)*IS2;
      E1[248+k]=wD1*dx; E1[264+k]=wD1*dy; E1[280+k]=wD1*dz;
    }

    if (c < 16){
      float A0=0.f, A1=0.f;
#pragma unroll
      for (int k4=0;k4<8;++k4){
        float4 w = *reinterpret_cast<const float4*>(&SH[CA_VVA + c*36 + k4*4]);
        float4 t0 = *reinterpret_cast<const float4*>(&E0[152+k4*4]);
        float4 t1 = *reinterpret_cast<const float4*>(&E1[152+k4*4]);
        A0 += dot4(t0,w); A1 += dot4(t1,w);
      }
      E0[184+c]=A0; E1[184+c]=A1;
    }

    {
      int d0=c/3, x0=c-3*d0;
      float v00 = E0[184+d0]*E0[97+x0];
      float v10 = E1[184+d0]*E1[97+x0];
#pragma unroll
      for (int k4=0;k4<4;++k4){
        float4 wb = *reinterpret_cast<const float4*>(&SH[CA_VVB + d0*20 + k4*4]);
        float4 wc = *reinterpret_cast<const float4*>(&SH[CA_VVC + d0*20 + k4*4]);
        float4 pp0 = *reinterpret_cast<const float4*>(&E0[200 + x0*16 + k4*4]);
        float4 qq0 = *reinterpret_cast<const float4*>(&E0[248 + x0*16 + k4*4]);
        float4 pp1 = *reinterpret_cast<const float4*>(&E1[200 + x0*16 + k4*4]);
        float4 qq1 = *reinterpret_cast<const float4*>(&E1[248 + x0*16 + k4*4]);
        v00 += dot4(pp0,wb) + dot4(qq0,wc);
        v10 += dot4(pp1,wb) + dot4(qq1,wc);
      }
      E0[344+c]=v00; E1[344+c]=v10;
      if (c < 16){
        int l=32+c, d1=l/3, x1=l-3*d1;
        float v01 = E0[184+d1]*E0[97+x1];
        float v11 = E1[184+d1]*E1[97+x1];
#pragma unroll
        for (int k4=0;k4<4;++k4){
          float4 wb = *reinterpret_cast<const float4*>(&SH[CA_VVB + d1*20 + k4*4]);
          float4 wc = *reinterpret_cast<const float4*>(&SH[CA_VVC + d1*20 + k4*4]);
          float4 pp0 = *reinterpret_cast<const float4*>(&E0[200 + x1*16 + k4*4]);
          float4 qq0 = *reinterpret_cast<const float4*>(&E0[248 + x1*16 + k4*4]);
          float4 pp1 = *reinterpret_cast<const float4*>(&E1[200 + x1*16 + k4*4]);
          float4 qq1 = *reinterpret_cast<const float4*>(&E1[248 + x1*16 + k4*4]);
          v01 += dot4(pp0,wb) + dot4(qq0,wc);
          v11 += dot4(pp1,wb) + dot4(qq1,wc);
        }
        E0[344+l]=v01; E1[344+l]=v11;
      }
    }

    float av0=0.f, av1=0.f;
#pragma unroll
    for (int k4=0;k4<12;++k4){
      float4 w = *reinterpret_cast<const float4*>(&SH[CA_VALS + c*52 + k4*4]);
      float4 m0 = *reinterpret_cast<const float4*>(&E0[104+k4*4]);
      float4 m1 = *reinterpret_cast<const float4*>(&E1[104+k4*4]);
      av0 += dot4(m0,w); av1 += dot4(m1,w);
    }
    E0[296+c]=av0; E1[296+c]=av1;

    if (c < 16){
      float g0=0.f, g1=0.f;
#pragma unroll
      for (int k4=0;k4<8;++k4){
        float4 w = *reinterpret_cast<const float4*>(&SH[CA_G + c*36 + k4*4]);
        float4 v0 = *reinterpret_cast<const float4*>(&E0[296+k4*4]);
        float4 v1 = *reinterpret_cast<const float4*>(&E1[296+k4*4]);
        g0 += dot4(v0,w); g1 += dot4(v1,w);
      }
      E0[328+c]=sigm(g0); E1[328+c]=sigm(g1);
    }

    float* er0 = wflat + (size_t)p0*160;
    float* er1 = wflat + (size_t)p1*160;
    er0[c] = av0 * sigm(av0);
    er1[c] = av1 * sigm(av1);
    er0[32+c] = E0[344+c]*E0[328+c/3];
    er1[32+c] = E1[344+c]*E1[328+c/3];
    if (c < 16){
      int l = 32+c;
      er0[64+c] = E0[344+l]*E0[328+l/3];
      er1[64+c] = E1[344+l]*E1[328+l/3];
    }
    if (c < 8){
      er0[80+c] = (c<4) ? E0[100+c] : E0[96+c-4];
      er1[80+c] = (c<4) ? E1[100+c] : E1[96+c-4];
    }
  }
}

// ============ edge value pass B: 2 edges per group, shared weight reads =====
#define CB_VLS  0      // [64][52]
#define CB_VLVA 3328   // [32][36]
#define CB_VLVB 4480   // [32][20]
#define CB_VLVC 5120   // [32][20]
#define CB_W2   5760   // [112]
#define CB_EDG  5872
#define CB_ESTR 240
// E: 0:vvg[48] 48:a[4] 52:y[4] 56:vs2[48] 104:t2[32]
//    136:p2x[16] 152:p2y 168:p2z 184:q2x 200:q2y 216:q2z

__global__ __launch_bounds__(256) void k_edgeCb(
    const float* __restrict__ Wvls, const float* __restrict__ Wvlv,
    const float* __restrict__ w2, float* __restrict__ wflat)
{
  __shared__ __align__(16) float SH[CB_EDG + 16*CB_ESTR];
  const int t = threadIdx.x;
  for (int i=t; i<64*48; i+=256){ int d=i/48, k=i-48*d; SH[CB_VLS+d*52+k] = Wvls[k*64+d]; }
  for (int i=t; i<32*32; i+=256){ int d=i>>5, k=i&31; SH[CB_VLVA+d*36+k] = Wvlv[k*32+d]; }
  for (int i=t; i<32*16; i+=256){ int d=i>>4, k=i&15; SH[CB_VLVB+d*20+k] = Wvlv[(32+k)*32+d]; }
  for (int i=t; i<32*16; i+=256){ int d=i>>4, k=i&15; SH[CB_VLVC+d*20+k] = Wvlv[(48+k)*32+d]; }
  for (int i=t; i<112;   i+=256){ SH[CB_W2+i] = w2[i]; }
  __syncthreads();

  const int g = t >> 5;
  const int c = t & 31;
  float* E0 = &SH[CB_EDG + (2*g)*CB_ESTR];
  float* E1 = E0 + CB_ESTR;
  const float IS3 = 0.57735026918962576f;
  const float IS2 = 0.70710678118654752f;

#pragma unroll 1
  for (int tile=0; tile<8; ++tile){
    const int p0 = blockIdx.x*128 + tile*16 + 2*g;
    const int p1 = p0 + 1;
    float* wr0 = wflat + (size_t)p0*160;
    float* wr1 = wflat + (size_t)p1*160;

    const float vs0 = wr0[c];
    const float vs1 = wr1[c];
    E0[c] = wr0[32+c];            E1[c] = wr1[32+c];
    if (c < 16){ E0[32+c] = wr0[64+c]; E1[32+c] = wr1[64+c]; }
    if (c < 8) { E0[48+c] = wr0[80+c]; E1[48+c] = wr1[80+c]; }

    const float ya0=E0[52], yax=E0[53], yay=E0[54], yaz=E0[55];
    const float yb0=E1[52], ybx=E1[53], yby=E1[54], ybz=E1[55];

    const float w2t = SH[CB_W2+32+c], w2s = SH[CB_W2+c];
    E0[104+c] = w2t*vs0;          E1[104+c] = w2t*vs1;
    E0[56+c]  = w2s*vs0*ya0;      E1[56+c]  = w2s*vs1*yb0;
    if (c >= 16){
      int k = c-16;
      float w2d = SH[CB_W2+80+k];
      float gx=E0[k*3], gy=E0[k*3+1], gz=E0[k*3+2];
      E0[88+k] = w2d*(gx*yax+gy*yay+gz*yaz)*IS3;
      float hx=E1[k*3], hy=E1[k*3+1], hz=E1[k*3+2];
      E1[88+k] = w2d*(hx*ybx+hy*yby+hz*ybz)*IS3;
    }
    if (c < 16){
      int k = c;
      float w2v = SH[CB_W2+64+k], wq = SH[CB_W2+96+k];
      float gx=E0[k*3], gy=E0[k*3+1], gz=E0[k*3+2];
      float u0 = w2v*ya0;
      E0[136+k]=u0*gx; E0[152+k]=u0*gy; E0[168+k]=u0*gz;
      float cx=(gy*yaz - gz*yay)*IS2;
      float cy=(gz*yax - gx*yaz)*IS2;
      float cz=(gx*yay - gy*yax)*IS2;
      E0[184+k]=wq*cx; E0[200+k]=wq*cy; E0[216+k]=wq*cz;
      float hx=E1[k*3], hy=E1[k*3+1], hz=E1[k*3+2];
      float u1 = w2v*yb0;
      E1[136+k]=u1*hx; E1[152+k]=u1*hy; E1[168+k]=u1*hz;
      float dx=(hy*ybz - hz*yby)*IS2;
      float dy=(hz*ybx - hx*ybz)*IS2;
      float dz=(hx*yby - hy*ybx)*IS2;
      E1[184+k]=wq*dx; E1[200+k]=wq*dy; E1[216+k]=wq*dz;
    }

    const float a00=E0[48], a01=E0[49], a02=E0[50], a03=E0[51];
    const float a10=E1[48], a11=E1[49], a12=E1[50], a13=E1[51];

    // flat_s: VLS rows c and 32+c read once for both edges
    {
      float f00=0.f, f01=0.f, f10=0.f, f11=0.f;
#pragma unroll
      for (int k4=0;k4<12;++k4){
        float4 wa = *reinterpret_cast<const float4*>(&SH[CB_VLS + c*52 + k4*4]);
        float4 wb = *reinterpret_cast<const float4*>(&SH[CB_VLS + (32+c)*52 + k4*4]);
        float4 v0 = *reinterpret_cast<const float4*>(&E0[56+k4*4]);
        float4 v1 = *reinterpret_cast<const float4*>(&E1[56+k4*4]);
        f00 += dot4(v0,wa); f01 += dot4(v0,wb);
        f10 += dot4(v1,wa); f11 += dot4(v1,wb);
      }
      wr0[c]    = f00*a00;
      wr0[32+c] = f01*((c<8)?a00:a01);
      wr1[c]    = f10*a10;
      wr1[32+c] = f11*((c<8)?a10:a11);
    }

    // flat_v: VLVA/VLVB/VLVC rows read once for both edges
    {
      float A20=0.f, A21=0.f;
#pragma unroll
      for (int k4=0;k4<8;++k4){
        float4 w = *reinterpret_cast<const float4*>(&SH[CB_VLVA + c*36 + k4*4]);
        float4 t0 = *reinterpret_cast<const float4*>(&E0[104+k4*4]);
        float4 t1 = *reinterpret_cast<const float4*>(&E1[104+k4*4]);
        A20 += dot4(t0,w); A21 += dot4(t1,w);
      }
      float b00=A20*yax, b01=A20*yay, b02=A20*yaz;
      float b10=A21*ybx, b11=A21*yby, b12=A21*ybz;
#pragma unroll
      for (int k4=0;k4<4;++k4){
        float4 wb = *reinterpret_cast<const float4*>(&SH[CB_VLVB + c*20 + k4*4]);
        float4 wc = *reinterpret_cast<const float4*>(&SH[CB_VLVC + c*20 + k4*4]);
        float4 p00 = *reinterpret_cast<const float4*>(&E0[136 + k4*4]);
        float4 p01 = *reinterpret_cast<const float4*>(&E0[152 + k4*4]);
        float4 p02 = *reinterpret_cast<const float4*>(&E0[168 + k4*4]);
        float4 q00 = *reinterpret_cast<const float4*>(&E0[184 + k4*4]);
        float4 q01 = *reinterpret_cast<const float4*>(&E0[200 + k4*4]);
        float4 q02 = *reinterpret_cast<const float4*>(&E0[216 + k4*4]);
        float4 p10 = *reinterpret_cast<const float4*>(&E1[136 + k4*4]);
        float4 p11 = *reinterpret_cast<const float4*>(&E1[152 + k4*4]);
        float4 p12 = *reinterpret_cast<const float4*>(&E1[168 + k4*4]);
        float4 q10 = *reinterpret_cast<const float4*>(&E1[184 + k4*4]);
        float4 q11 = *reinterpret_cast<const float4*>(&E1[200 + k4*4]);
        float4 q12 = *reinterpret_cast<const float4*>(&E1[216 + k4*4]);
        b00 += dot4(p00,wb) + dot4(q00,wc);
        b01 += dot4(p01,wb) + dot4(q01,wc);
        b02 += dot4(p02,wb) + dot4(q02,wc);
        b10 += dot4(p10,wb) + dot4(q10,wc);
        b11 += dot4(p11,wb) + dot4(q11,wc);
        b12 += dot4(p12,wb) + dot4(q12,wc);
      }
      int o = 64 + c*3;
      float aw00 = (o   < 80) ? a01 : ((o   < 120) ? a02 : a03);
      float aw01 = (o+1 < 80) ? a01 : ((o+1 < 120) ? a02 : a03);
      float aw02 = (o+2 < 80) ? a01 : ((o+2 < 120) ? a02 : a03);
      float aw10 = (o   < 80) ? a11 : ((o   < 120) ? a12 : a13);
      float aw11 = (o+1 < 80) ? a11 : ((o+1 < 120) ? a12 : a13);
      float aw12 = (o+2 < 80) ? a11 : ((o+2 < 120) ? a12 : a13);
      wr0[o]   = b00*aw00;
      wr0[o+1] = b01*aw01;
      wr0[o+2] = b02*aw02;
      wr1[o]   = b10*aw10;
      wr1[o+1] = b11*aw11;
      wr1[o+2] = b12*aw12;
    }
  }
}

// ------------- gather: per-dst sum of weighted per-edge rows ---------------
__global__ __launch_bounds__(256) void k_gather(
    const int* __restrict__ base, const int* __restrict__ deg,
    const float* __restrict__ wflat, float* __restrict__ agg)
{
  int id = blockIdx.x*256 + threadIdx.x;
  if (id >= NN*40) return;
  int d = id / 40, c = id % 40;
  int b = base[d], n = deg[d];
  float4 acc = make_float4(0.f,0.f,0.f,0.f);
  for (int i=0;i<n;++i){
    float4 w = reinterpret_cast<const float4*>(wflat + (size_t)(b+i)*160)[c];
    acc.x += w.x; acc.y += w.y; acc.z += w.z; acc.w += w.w;
  }
  reinterpret_cast<float4*>(agg + (size_t)d*160)[c] = acc;
}

// ------------- output pass: Wp projections + residual ----------------------
__global__ __launch_bounds__(256) void k_out(
    const float* __restrict__ node, const float* __restrict__ agg,
    const float* __restrict__ Wps, const float* __restrict__ Wpv,
    float* __restrict__ out)
{
  int n = blockIdx.x * 256 + threadIdx.x;
  if (n >= NN) return;
  const float* ar = agg + (size_t)n*160;
  const float* nr = node + (size_t)n*80;
  float* orow = out + (size_t)n*80;

  float a[64];
  { const float4* ap = reinterpret_cast<const float4*>(ar);
#pragma unroll
    for (int i=0;i<16;++i){ float4 t=ap[i];
      a[i*4]=t.x; a[i*4+1]=t.y; a[i*4+2]=t.z; a[i*4+3]=t.w; } }
#pragma unroll 1
  for (int d=0; d<32; ++d){
    float acc=0.f;
#pragma unroll
    for (int c=0;c<64;++c) acc += a[c]*Wps[c*32+d];
    orow[d] = nr[d] + acc;
  }
  float b[96];
  { const float4* bp = reinterpret_cast<const float4*>(ar + 64);
#pragma unroll
    for (int i=0;i<24;++i){ float4 t=bp[i];
      b[i*4]=t.x; b[i*4+1]=t.y; b[i*4+2]=t.z; b[i*4+3]=t.w; } }
#pragma unroll 1
  for (int d=0; d<16; ++d){
#pragma unroll
    for (int x=0;x<3;++x){
      float acc=0.f;
#pragma unroll
      for (int c=0;c<32;++c) acc += b[c*3+x]*Wpv[c*16+d];
      orow[32+d*3+x] = nr[32+d*3+x] + acc;
    }
  }
}

extern "C" void kernel_launch(void* const* d_in, const int* in_sizes, int n_in,
                              void* d_out, int out_size, void* d_ws, size_t ws_size,
                              hipStream_t stream)
{
  const float* node   = (const float*)d_in[0];
  const float* rbf    = (const float*)d_in[1];
  const float* rsh    = (const float*)d_in[2];
  const float* Wsrc_s = (const float*)d_in[3];
  const float* Wsrc_v = (const float*)d_in[4];
  const float* Wdst_s = (const float*)d_in[5];
  const float* Wdst_v = (const float*)d_in[6];
  const float* W_rbf  = (const float*)d_in[7];
  const float* dtp2   = (const float*)d_in[8];
  const float* Wa     = (const float*)d_in[9];
  const float* adot   = (const float*)d_in[10];
  const float* Wval_s = (const float*)d_in[11];
  const float* Wval_v = (const float*)d_in[12];
  const float* Wg     = (const float*)d_in[13];
  const float* Wvl_s  = (const float*)d_in[14];
  const float* Wvl_v  = (const float*)d_in[15];
  const float* Wp_s   = (const float*)d_in[16];
  const float* Wp_v   = (const float*)d_in[17];
  const int*   ei     = (const int*)d_in[18];

  float* ws = (float*)d_ws;

  size_t off = 0;
  float* ss   = ws + off; off += (size_t)NN*32;
  float* ds   = ws + off; off += (size_t)NN*32;
  float* sv   = ws + off; off += (size_t)NN*48;
  float* dv   = ws + off; off += (size_t)NN*48;
  float* lg   = ws + off; off += (size_t)EE*4;
  float* m    = ws + off; off += (size_t)NN*4;
  float* iden = ws + off; off += (size_t)NN*4;
  int* deg    = (int*)(ws + off); off += (size_t)NN;
  int* base   = (int*)(ws + off); off += (size_t)NN;
  int* cursor = (int*)(ws + off); off += (size_t)NN;
  int* csr    = (int*)(ws + off); off += (size_t)EE;
  float* agg  = ws + off; off += (size_t)NN*160;
  float* wflat= ws + off; off += (size_t)EE*160;
  size_t need_new = off * sizeof(float);
  if (ws_size < need_new) return;

  hipMemsetAsync(deg, 0, (size_t)NN*sizeof(int), stream);
  k_node   <<<NN/256, 256, 0, stream>>>(node, Wsrc_s, Wsrc_v, Wdst_s, Wdst_v, ss, ds, sv, dv);
  k_hist   <<<EE/256, 256, 0, stream>>>(ei, deg);
  k_scan   <<<1, 1024, 0, stream>>>(deg, base, cursor);
  k_scatter<<<EE/256, 256, 0, stream>>>(ei, cursor, csr);
  k_edgeA2 <<<EE/256, 512, 0, stream>>>(ei, rbf, rsh, W_rbf, Wa, adot, ss, ds, sv, dv, lg);
  k_soft   <<<(NN*4)/256, 256, 0, stream>>>(base, deg, csr, lg, m, iden);
  k_edgeCa <<<EE/128, 256, 0, stream>>>(csr, ei, rbf, rsh, W_rbf, Wval_s, Wval_v, Wg,
                                        ss, ds, sv, dv, lg, m, iden, wflat);
  k_edgeCb <<<EE/128, 256, 0, stream>>>(Wvl_s, Wvl_v, dtp2, wflat);
  k_gather <<<(NN*40)/256, 256, 0, stream>>>(base, deg, wflat, agg);
  k_out    <<<NN/256, 256, 0, stream>>>(node, agg, Wp_s, Wp_v, (float*)d_out);
}

// Round 10
// 507.202 us; speedup vs baseline: 1.2948x; 1.0285x over previous
//
#include <hip/hip_runtime.h>

#define NN 32768
#define EE 262144

static __device__ __forceinline__ float sigm(float x){
  return 1.0f / (1.0f + __expf(-x));
}
static __device__ __forceinline__ float dot4(float4 a, float4 b){
  return a.x*b.x + a.y*b.y + a.z*b.z + a.w*b.w;
}
static __device__ __forceinline__ unsigned short f2bf(float x){
  unsigned u = __float_as_uint(x);
  u += 0x7FFFu + ((u >> 16) & 1u);   // round to nearest even
  return (unsigned short)(u >> 16);
}
static __device__ __forceinline__ float bf2f(unsigned short b){
  return __uint_as_float(((unsigned)b) << 16);
}

// ---------------- node pass: o3-layernorm + src/dst linears ----------------
__global__ __launch_bounds__(256) void k_node(
    const float* __restrict__ node,
    const float* __restrict__ Wss, const float* __restrict__ Wsv,
    const float* __restrict__ Wds, const float* __restrict__ Wdv,
    float* __restrict__ ss, float* __restrict__ ds,
    float* __restrict__ sv, float* __restrict__ dv)
{
  int n = blockIdx.x * 256 + threadIdx.x;
  if (n >= NN) return;
  const float4* row = reinterpret_cast<const float4*>(node + (size_t)n * 80);
  float s[32], v[48];
#pragma unroll
  for (int i = 0; i < 8; ++i){
    float4 t = row[i];
    s[i*4+0]=t.x; s[i*4+1]=t.y; s[i*4+2]=t.z; s[i*4+3]=t.w;
  }
#pragma unroll
  for (int i = 0; i < 12; ++i){
    float4 t = row[8+i];
    v[i*4+0]=t.x; v[i*4+1]=t.y; v[i*4+2]=t.z; v[i*4+3]=t.w;
  }
  float mean = 0.f;
#pragma unroll
  for (int i=0;i<32;++i) mean += s[i];
  mean *= (1.0f/32.0f);
  float var = 0.f;
#pragma unroll
  for (int i=0;i<32;++i){ float d0 = s[i]-mean; var += d0*d0; }
  var *= (1.0f/32.0f);
  float sinv = rsqrtf(var + 1e-5f);
#pragma unroll
  for (int i=0;i<32;++i) s[i] = (s[i]-mean)*sinv;
  float n2 = 0.f;
#pragma unroll
  for (int i=0;i<48;++i) n2 += v[i]*v[i];
  n2 *= (1.0f/16.0f);
  float vinv = rsqrtf(n2 + 1e-5f);
#pragma unroll
  for (int i=0;i<48;++i) v[i] *= vinv;

  float* ssr = ss + (size_t)n*32;
  float* dsr = ds + (size_t)n*32;
#pragma unroll 1
  for (int d=0; d<32; ++d){
    float a=0.f, b=0.f;
#pragma unroll
    for (int c=0;c<32;++c){ a += s[c]*Wss[c*32+d]; b += s[c]*Wds[c*32+d]; }
    ssr[d]=a; dsr[d]=b;
  }
  float* svr = sv + (size_t)n*48;
  float* dvr = dv + (size_t)n*48;
#pragma unroll 1
  for (int d=0; d<16; ++d){
#pragma unroll
    for (int x=0;x<3;++x){
      float a=0.f, b=0.f;
#pragma unroll
      for (int c=0;c<16;++c){ a += v[c*3+x]*Wsv[c*16+d]; b += v[c*3+x]*Wdv[c*16+d]; }
      svr[d*3+x]=a; dvr[d*3+x]=b;
    }
  }
}

// ---------------- CSR build ----------------
__global__ __launch_bounds__(256) void k_hist(const int* __restrict__ ei, int* __restrict__ deg){
  int e = blockIdx.x*256 + threadIdx.x;
  if (e >= EE) return;
  atomicAdd(deg + ei[EE + e], 1);
}

__global__ __launch_bounds__(1024) void k_scan(const int* __restrict__ deg,
                                               int* __restrict__ base, int* __restrict__ cursor){
  __shared__ int lds[1024];
  int t = threadIdx.x;
  int v[32];
#pragma unroll
  for (int i=0;i<32;++i) v[i] = deg[t*32+i];
  int run = 0;
#pragma unroll
  for (int i=0;i<32;++i){ int x=v[i]; v[i]=run; run+=x; }
  lds[t]=run; __syncthreads();
  for (int off=1; off<1024; off<<=1){
    int add = (t>=off) ? lds[t-off] : 0;
    __syncthreads();
    lds[t] += add;
    __syncthreads();
  }
  int pre = (t==0) ? 0 : lds[t-1];
#pragma unroll
  for (int i=0;i<32;++i){ int b = pre + v[i]; base[t*32+i]=b; cursor[t*32+i]=b; }
}

__global__ __launch_bounds__(256) void k_scatter(const int* __restrict__ ei,
                                                 int* __restrict__ cursor, int* __restrict__ csr){
  int e = blockIdx.x*256 + threadIdx.x;
  if (e >= EE) return;
  int d = ei[EE + e];
  int pos = atomicAdd(cursor + d, 1);
  csr[pos] = e;
}

// ============== cooperative edge pass A: 2 edges per 32-lane group =========
#define A_RBFA 0      // [32][20]
#define A_RBFD 640    // [16][20]
#define A_WA   960    // [64][52]
#define A_ADOT 4288
#define A_EDG  4352
#define A_ESTR 152

__global__ __launch_bounds__(512) void k_edgeA2(
    const int* __restrict__ ei,
    const float* __restrict__ rbf, const float* __restrict__ rsh,
    const float* __restrict__ Wrbf, const float* __restrict__ Wa,
    const float* __restrict__ adot,
    const float* __restrict__ ss, const float* __restrict__ ds,
    const float* __restrict__ sv, const float* __restrict__ dv,
    float* __restrict__ logits)
{
  __shared__ __align__(16) float SH[A_EDG + 32*A_ESTR];
  const int t = threadIdx.x;
  for (int i=t; i<32*16; i+=512){ int row=i>>4, j=i&15; SH[A_RBFA+row*20+j] = Wrbf[j*112+row]; }
  for (int i=t; i<16*16; i+=512){ int row=i>>4, j=i&15; SH[A_RBFD+row*20+j] = Wrbf[j*112+80+row]; }
  for (int i=t; i<64*48; i+=512){ int o=i/48, k=i-48*o; SH[A_WA+o*52+k] = Wa[k*64+o]; }
  for (int i=t; i<64;    i+=512){ SH[A_ADOT+i] = adot[i]; }
  __syncthreads();

  const int g = t >> 5;
  const int c = t & 31;
  float* E0 = &SH[A_EDG + (2*g)*A_ESTR];
  float* E1 = E0 + A_ESTR;
  const float IS3 = 0.57735026918962576f;

#pragma unroll 1
  for (int tile=0; tile<8; ++tile){
    const int e0 = blockIdx.x*256 + tile*32 + 2*g;
    const int e1 = e0 + 1;
    const int s0i = ei[e0], d0i = ei[EE + e0];
    const int s1i = ei[e1], d1i = ei[EE + e1];

    if (c < 8){
      float4 a = *reinterpret_cast<const float4*>(ss + (size_t)s0i*32 + c*4);
      float4 b = *reinterpret_cast<const float4*>(ds + (size_t)d0i*32 + c*4);
      float4 o; o.x=a.x+b.x; o.y=a.y+b.y; o.z=a.z+b.z; o.w=a.w+b.w;
      *reinterpret_cast<float4*>(&E0[c*4]) = o;
      float4 a2 = *reinterpret_cast<const float4*>(ss + (size_t)s1i*32 + c*4);
      float4 b2 = *reinterpret_cast<const float4*>(ds + (size_t)d1i*32 + c*4);
      float4 o2; o2.x=a2.x+b2.x; o2.y=a2.y+b2.y; o2.z=a2.z+b2.z; o2.w=a2.w+b2.w;
      *reinterpret_cast<float4*>(&E1[c*4]) = o2;
    } else if (c < 20){
      int i = c-8;
      float4 a = *reinterpret_cast<const float4*>(sv + (size_t)s0i*48 + i*4);
      float4 b = *reinterpret_cast<const float4*>(dv + (size_t)d0i*48 + i*4);
      float4 o; o.x=a.x+b.x; o.y=a.y+b.y; o.z=a.z+b.z; o.w=a.w+b.w;
      *reinterpret_cast<float4*>(&E0[32+i*4]) = o;
      float4 a2 = *reinterpret_cast<const float4*>(sv + (size_t)s1i*48 + i*4);
      float4 b2 = *reinterpret_cast<const float4*>(dv + (size_t)d1i*48 + i*4);
      float4 o2; o2.x=a2.x+b2.x; o2.y=a2.y+b2.y; o2.z=a2.z+b2.z; o2.w=a2.w+b2.w;
      *reinterpret_cast<float4*>(&E1[32+i*4]) = o2;
    } else if (c < 24){
      int i = c-20;
      *reinterpret_cast<float4*>(&E0[80+i*4]) =
          *reinterpret_cast<const float4*>(rbf + (size_t)e0*16 + i*4);
      *reinterpret_cast<float4*>(&E1[80+i*4]) =
          *reinterpret_cast<const float4*>(rbf + (size_t)e1*16 + i*4);
    } else if (c == 24){
      *reinterpret_cast<float4*>(&E0[96]) =
          *reinterpret_cast<const float4*>(rsh + (size_t)e0*4);
      *reinterpret_cast<float4*>(&E1[96]) =
          *reinterpret_cast<const float4*>(rsh + (size_t)e1*4);
    }

    float rr0[16], rr1[16];
#pragma unroll
    for (int i=0;i<4;++i){
      *reinterpret_cast<float4*>(&rr0[i*4]) = *reinterpret_cast<const float4*>(&E0[80+i*4]);
      *reinterpret_cast<float4*>(&rr1[i*4]) = *reinterpret_cast<const float4*>(&E1[80+i*4]);
    }
    const float ya0=E0[96], yax=E0[97], yay=E0[98], yaz=E0[99];
    const float yb0=E1[96], ybx=E1[97], yby=E1[98], ybz=E1[99];
    {
      float wA0=0.f, wA1=0.f;
#pragma unroll
      for (int j4=0;j4<4;++j4){
        float4 w = *reinterpret_cast<const float4*>(&SH[A_RBFA + c*20 + j4*4]);
        float4 r0 = *reinterpret_cast<const float4*>(&rr0[j4*4]);
        float4 r1 = *reinterpret_cast<const float4*>(&rr1[j4*4]);
        wA0 += dot4(r0,w); wA1 += dot4(r1,w);
      }
      E0[104+c] = wA0 * E0[c] * ya0;
      E1[104+c] = wA1 * E1[c] * yb0;
    }
    if (c < 16){
      float wD0=0.f, wD1=0.f;
#pragma unroll
      for (int j4=0;j4<4;++j4){
        float4 w = *reinterpret_cast<const float4*>(&SH[A_RBFD + c*20 + j4*4]);
        float4 r0 = *reinterpret_cast<const float4*>(&rr0[j4*4]);
        float4 r1 = *reinterpret_cast<const float4*>(&rr1[j4*4]);
        wD0 += dot4(r0,w); wD1 += dot4(r1,w);
      }
      float vx=E0[32+c*3], vy=E0[33+c*3], vz=E0[34+c*3];
      E0[136+c] = wD0 * (vx*yax + vy*yay + vz*yaz) * IS3;
      float ux=E1[32+c*3], uy=E1[33+c*3], uz=E1[34+c*3];
      E1[136+c] = wD1 * (ux*ybx + uy*yby + uz*ybz) * IS3;
    }

    float a00=0.f, a01=0.f, a10=0.f, a11=0.f;
#pragma unroll
    for (int k4=0;k4<12;++k4){
      float4 w0 = *reinterpret_cast<const float4*>(&SH[A_WA + c*52 + k4*4]);
      float4 w1 = *reinterpret_cast<const float4*>(&SH[A_WA + (32+c)*52 + k4*4]);
      float4 m0 = *reinterpret_cast<const float4*>(&E0[104+k4*4]);
      float4 m1 = *reinterpret_cast<const float4*>(&E1[104+k4*4]);
      a00 += dot4(m0,w0); a01 += dot4(m0,w1);
      a10 += dot4(m1,w0); a11 += dot4(m1,w1);
    }
    const float ad0 = SH[A_ADOT+c], ad1 = SH[A_ADOT+32+c];
    a00 = ((a00 > 0.f) ? a00 : 0.2f*a00) * ad0;
    a01 = ((a01 > 0.f) ? a01 : 0.2f*a01) * ad1;
    a10 = ((a10 > 0.f) ? a10 : 0.2f*a10) * ad0;
    a11 = ((a11 > 0.f) ? a11 : 0.2f*a11) * ad1;
#pragma unroll
    for (int msk=8; msk>=1; msk>>=1){
      a00 += __shfl_xor(a00, msk);
      a01 += __shfl_xor(a01, msk);
      a10 += __shfl_xor(a10, msk);
      a11 += __shfl_xor(a11, msk);
    }
    if ((c & 15) == 0){
      int h0 = c >> 4;
      logits[(size_t)e0*4 + h0]     = a00;
      logits[(size_t)e0*4 + 2 + h0] = a01;
      logits[(size_t)e1*4 + h0]     = a10;
      logits[(size_t)e1*4 + 2 + h0] = a11;
    }
  }
}

// ------------- per-(dst,head) softmax stats via CSR (no atomics) ----------
__global__ __launch_bounds__(256) void k_soft(
    const int* __restrict__ base, const int* __restrict__ deg,
    const int* __restrict__ csr, const float* __restrict__ logits,
    float* __restrict__ m, float* __restrict__ iden)
{
  int id = blockIdx.x*256 + threadIdx.x;
  if (id >= NN*4) return;
  int d = id >> 2, h = id & 3;
  int b = base[d], n = deg[d];
  float mm = -3.4e38f;
  for (int i=0;i<n;++i){ int e = csr[b+i]; mm = fmaxf(mm, logits[(size_t)e*4+h]); }
  float s = 0.f;
  for (int i=0;i<n;++i){ int e = csr[b+i]; s += __expf(logits[(size_t)e*4+h] - mm); }
  m[id] = mm;
  iden[id] = (n>0) ? 1.0f/s : 0.f;
}

// ============ edge value pass A: 2 edges/group, bf16 output =================
// wa row (96 bf16 = 192 B): [0:32) vsg bf16, [32:80) vvg bf16,
// bytes [160:176) alpha f32x4, [176:192) y f32x4.
#define CA_RBF  0      // [112][20]
#define CA_VALS 2240   // [32][52]
#define CA_VVA  3904   // [16][36]
#define CA_VVB  4480   // [16][20]
#define CA_VVC  4800   // [16][20]
#define CA_G    5120   // [16][36]
#define CA_EDG  5696
#define CA_ESTR 400

__global__ __launch_bounds__(256) void k_edgeCa(
    const int* __restrict__ csr, const int* __restrict__ ei,
    const float* __restrict__ rbf, const float* __restrict__ rsh,
    const float* __restrict__ Wrbf,
    const float* __restrict__ Wvals, const float* __restrict__ Wvalv,
    const float* __restrict__ Wg,
    const float* __restrict__ ss, const float* __restrict__ ds,
    const float* __restrict__ sv, const float* __restrict__ dv,
    const float* __restrict__ logits, const float* __restrict__ m,
    const float* __restrict__ iden, unsigned short* __restrict__ wa)
{
  __shared__ __align__(16) float SH[CA_EDG + 16*CA_ESTR];
  const int t = threadIdx.x;
  for (int i=t; i<112*16; i+=256){ int d=i>>4, k=i&15; SH[CA_RBF+d*20+k]  = Wrbf[k*112+d]; }
  for (int i=t; i<32*48;  i+=256){ int d=i/48, k=i-48*d; SH[CA_VALS+d*52+k] = Wvals[k*32+d]; }
  for (int i=t; i<16*32;  i+=256){ int d=i>>5, k=i&31; SH[CA_VVA+d*36+k]  = Wvalv[k*16+d]; }
  for (int i=t; i<16*16;  i+=256){ int d=i>>4, k=i&15; SH[CA_VVB+d*20+k]  = Wvalv[(32+k)*16+d]; }
  for (int i=t; i<16*16;  i+=256){ int d=i>>4, k=i&15; SH[CA_VVC+d*20+k]  = Wvalv[(48+k)*16+d]; }
  for (int i=t; i<16*32;  i+=256){ int d=i>>5, k=i&31; SH[CA_G+d*36+k]    = Wg[k*16+d]; }
  __syncthreads();

  const int g = t >> 5;
  const int c = t & 31;
  float* E0 = &SH[CA_EDG + (2*g)*CA_ESTR];
  float* E1 = E0 + CA_ESTR;
  const float IS3 = 0.57735026918962576f;
  const float IS2 = 0.70710678118654752f;

#pragma unroll 1
  for (int tile=0; tile<8; ++tile){
    const int p0 = blockIdx.x*128 + tile*16 + 2*g;
    const int p1 = p0 + 1;
    const int ea = csr[p0], eb = csr[p1];
    const int sa = ei[ea], da = ei[EE + ea];
    const int sb = ei[eb], db = ei[EE + eb];

    if (c < 8){
      float4 a = *reinterpret_cast<const float4*>(ss + (size_t)sa*32 + c*4);
      float4 b = *reinterpret_cast<const float4*>(ds + (size_t)da*32 + c*4);
      float4 o; o.x=a.x+b.x; o.y=a.y+b.y; o.z=a.z+b.z; o.w=a.w+b.w;
      *reinterpret_cast<float4*>(&E0[c*4]) = o;
      float4 a2 = *reinterpret_cast<const float4*>(ss + (size_t)sb*32 + c*4);
      float4 b2 = *reinterpret_cast<const float4*>(ds + (size_t)db*32 + c*4);
      float4 o2; o2.x=a2.x+b2.x; o2.y=a2.y+b2.y; o2.z=a2.z+b2.z; o2.w=a2.w+b2.w;
      *reinterpret_cast<float4*>(&E1[c*4]) = o2;
    } else if (c < 20){
      int i = c-8;
      float4 a = *reinterpret_cast<const float4*>(sv + (size_t)sa*48 + i*4);
      float4 b = *reinterpret_cast<const float4*>(dv + (size_t)da*48 + i*4);
      float4 o; o.x=a.x+b.x; o.y=a.y+b.y; o.z=a.z+b.z; o.w=a.w+b.w;
      *reinterpret_cast<float4*>(&E0[32+i*4]) = o;
      float4 a2 = *reinterpret_cast<const float4*>(sv + (size_t)sb*48 + i*4);
      float4 b2 = *reinterpret_cast<const float4*>(dv + (size_t)db*48 + i*4);
      float4 o2; o2.x=a2.x+b2.x; o2.y=a2.y+b2.y; o2.z=a2.z+b2.z; o2.w=a2.w+b2.w;
      *reinterpret_cast<float4*>(&E1[32+i*4]) = o2;
    } else if (c < 24){
      int i = c-20;
      *reinterpret_cast<float4*>(&E0[80+i*4]) =
          *reinterpret_cast<const float4*>(rbf + (size_t)ea*16 + i*4);
      *reinterpret_cast<float4*>(&E1[80+i*4]) =
          *reinterpret_cast<const float4*>(rbf + (size_t)eb*16 + i*4);
    } else if (c == 24){
      *reinterpret_cast<float4*>(&E0[96]) =
          *reinterpret_cast<const float4*>(rsh + (size_t)ea*4);
      *reinterpret_cast<float4*>(&E1[96]) =
          *reinterpret_cast<const float4*>(rsh + (size_t)eb*4);
    } else if (c == 25){
      float4 l4 = *reinterpret_cast<const float4*>(logits + (size_t)ea*4);
      float4 m4 = *reinterpret_cast<const float4*>(m + (size_t)da*4);
      float4 i4 = *reinterpret_cast<const float4*>(iden + (size_t)da*4);
      E0[100] = __expf(l4.x-m4.x)*i4.x;
      E0[101] = __expf(l4.y-m4.y)*i4.y;
      E0[102] = __expf(l4.z-m4.z)*i4.z;
      E0[103] = __expf(l4.w-m4.w)*i4.w;
      float4 l5 = *reinterpret_cast<const float4*>(logits + (size_t)eb*4);
      float4 m5 = *reinterpret_cast<const float4*>(m + (size_t)db*4);
      float4 i5 = *reinterpret_cast<const float4*>(iden + (size_t)db*4);
      E1[100] = __expf(l5.x-m5.x)*i5.x;
      E1[101] = __expf(l5.y-m5.y)*i5.y;
      E1[102] = __expf(l5.z-m5.z)*i5.z;
      E1[103] = __expf(l5.w-m5.w)*i5.w;
    }

    float rr0[16], rr1[16];
#pragma unroll
    for (int i=0;i<4;++i){
      *reinterpret_cast<float4*>(&rr0[i*4]) = *reinterpret_cast<const float4*>(&E0[80+i*4]);
      *reinterpret_cast<float4*>(&rr1[i*4]) = *reinterpret_cast<const float4*>(&E1[80+i*4]);
    }
    float wA0=0.f,wB0=0.f,wC0=0.f,wD0=0.f, wA1=0.f,wB1=0.f,wC1=0.f,wD1=0.f;
#pragma unroll
    for (int j4=0;j4<4;++j4){
      float4 a0 = *reinterpret_cast<const float4*>(&SH[CA_RBF + c*20           + j4*4]);
      float4 a1 = *reinterpret_cast<const float4*>(&SH[CA_RBF + (32+c)*20      + j4*4]);
      float4 a2 = *reinterpret_cast<const float4*>(&SH[CA_RBF + (64+c)*20      + j4*4]);
      float4 a3 = *reinterpret_cast<const float4*>(&SH[CA_RBF + (96+(c&15))*20 + j4*4]);
      float4 r0 = *reinterpret_cast<const float4*>(&rr0[j4*4]);
      float4 r1 = *reinterpret_cast<const float4*>(&rr1[j4*4]);
      wA0 += dot4(r0,a0); wA1 += dot4(r1,a0);
      wB0 += dot4(r0,a1); wB1 += dot4(r1,a1);
      wC0 += dot4(r0,a2); wC1 += dot4(r1,a2);
      wD0 += dot4(r0,a3); wD1 += dot4(r1,a3);
    }

    const float ya0=E0[96], yax=E0[97], yay=E0[98], yaz=E0[99];
    const float yb0=E1[96], ybx=E1[97], yby=E1[98], ybz=E1[99];
    const float sc0 = E0[c], sc1 = E1[c];
    E0[104+c] = wA0 * sc0 * ya0;   E1[104+c] = wA1 * sc1 * yb0;
    E0[152+c] = wB0 * sc0;         E1[152+c] = wB1 * sc1;
    if (c >= 16){
      int k = c-16;
      float vx=E0[32+k*3], vy=E0[33+k*3], vz=E0[34+k*3];
      E0[136+k] = wC0 * (vx*yax+vy*yay+vz*yaz) * IS3;
      float ux=E1[32+k*3], uy=E1[33+k*3], uz=E1[34+k*3];
      E1[136+k] = wC1 * (ux*ybx+uy*yby+uz*ybz) * IS3;
    }
    if (c < 16){
      int k = c;
      float vx=E0[32+k*3], vy=E0[33+k*3], vz=E0[34+k*3];
      float u0 = wC0 * ya0;
      E0[200+k]=u0*vx; E0[216+k]=u0*vy; E0[232+k]=u0*vz;
      float cx=(vy*yaz - vz*yay)*IS2;
      float cy=(vz*yax - vx*yaz)*IS2;
      float cz=(vx*yay - vy*yax)*IS2;
      E0[248+k]=wD0*cx; E0[264+k]=wD0*cy; E0[280+k]=wD0*cz;
      float ux=E1[32+k*3], uy=E1[33+k*3], uz=E1[34+k*3];
      float u1 = wC1 * yb0;
      E1[200+k]=u1*ux; E1[216+k]=u1*uy; E1[232+k]=u1*uz;
      float dx=(uy*ybz - uz*yby)*IS2;
      float dy=(uz*ybx - ux*ybz)*IS2;
      float dz=(ux*yby - uy*ybx)*IS2;
      E1[248+k]=wD1*dx; E1[264+k]=wD1*dy; E1[280+k]=wD1*dz;
    }

    if (c < 16){
      float A0=0.f, A1=0.f;
#pragma unroll
      for (int k4=0;k4<8;++k4){
        float4 w = *reinterpret_cast<const float4*>(&SH[CA_VVA + c*36 + k4*4]);
        float4 t0 = *reinterpret_cast<const float4*>(&E0[152+k4*4]);
        float4 t1 = *reinterpret_cast<const float4*>(&E1[152+k4*4]);
        A0 += dot4(t0,w); A1 += dot4(t1,w);
      }
      E0[184+c]=A0; E1[184+c]=A1;
    }

    {
      int d0=c/3, x0=c-3*d0;
      float v00 = E0[184+d0]*E0[97+x0];
      float v10 = E1[184+d0]*E1[97+x0];
#pragma unroll
      for (int k4=0;k4<4;++k4){
        float4 wb = *reinterpret_cast<const float4*>(&SH[CA_VVB + d0*20 + k4*4]);
        float4 wc = *reinterpret_cast<const float4*>(&SH[CA_VVC + d0*20 + k4*4]);
        float4 pp0 = *reinterpret_cast<const float4*>(&E0[200 + x0*16 + k4*4]);
        float4 qq0 = *reinterpret_cast<const float4*>(&E0[248 + x0*16 + k4*4]);
        float4 pp1 = *reinterpret_cast<const float4*>(&E1[200 + x0*16 + k4*4]);
        float4 qq1 = *reinterpret_cast<const float4*>(&E1[248 + x0*16 + k4*4]);
        v00 += dot4(pp0,wb) + dot4(qq0,wc);
        v10 += dot4(pp1,wb) + dot4(qq1,wc);
      }
      E0[344+c]=v00; E1[344+c]=v10;
      if (c < 16){
        int l=32+c, d1=l/3, x1=l-3*d1;
        float v01 = E0[184+d1]*E0[97+x1];
        float v11 = E1[184+d1]*E1[97+x1];
#pragma unroll
        for (int k4=0;k4<4;++k4){
          float4 wb = *reinterpret_cast<const float4*>(&SH[CA_VVB + d1*20 + k4*4]);
          float4 wc = *reinterpret_cast<const float4*>(&SH[CA_VVC + d1*20 + k4*4]);
          float4 pp0 = *reinterpret_cast<const float4*>(&E0[200 + x1*16 + k4*4]);
          float4 qq0 = *reinterpret_cast<const float4*>(&E0[248 + x1*16 + k4*4]);
          float4 pp1 = *reinterpret_cast<const float4*>(&E1[200 + x1*16 + k4*4]);
          float4 qq1 = *reinterpret_cast<const float4*>(&E1[248 + x1*16 + k4*4]);
          v01 += dot4(pp0,wb) + dot4(qq0,wc);
          v11 += dot4(pp1,wb) + dot4(qq1,wc);
        }
        E0[344+l]=v01; E1[344+l]=v11;
      }
    }

    float av0=0.f, av1=0.f;
#pragma unroll
    for (int k4=0;k4<12;++k4){
      float4 w = *reinterpret_cast<const float4*>(&SH[CA_VALS + c*52 + k4*4]);
      float4 m0 = *reinterpret_cast<const float4*>(&E0[104+k4*4]);
      float4 m1 = *reinterpret_cast<const float4*>(&E1[104+k4*4]);
      av0 += dot4(m0,w); av1 += dot4(m1,w);
    }
    E0[296+c]=av0; E1[296+c]=av1;

    if (c < 16){
      float g0=0.f, g1=0.f;
#pragma unroll
      for (int k4=0;k4<8;++k4){
        float4 w = *reinterpret_cast<const float4*>(&SH[CA_G + c*36 + k4*4]);
        float4 v0 = *reinterpret_cast<const float4*>(&E0[296+k4*4]);
        float4 v1 = *reinterpret_cast<const float4*>(&E1[296+k4*4]);
        g0 += dot4(v0,w); g1 += dot4(v1,w);
      }
      E0[328+c]=sigm(g0); E1[328+c]=sigm(g1);
    }

    unsigned short* er0 = wa + (size_t)p0*96;
    unsigned short* er1 = wa + (size_t)p1*96;
    er0[c] = f2bf(av0 * sigm(av0));
    er1[c] = f2bf(av1 * sigm(av1));
    er0[32+c] = f2bf(E0[344+c]*E0[328+c/3]);
    er1[32+c] = f2bf(E1[344+c]*E1[328+c/3]);
    if (c < 16){
      int l = 32+c;
      er0[64+c] = f2bf(E0[344+l]*E0[328+l/3]);
      er1[64+c] = f2bf(E1[344+l]*E1[328+l/3]);
    }
    if (c < 8){
      float v0 = (c<4) ? E0[100+c] : E0[96+c-4];
      float v1 = (c<4) ? E1[100+c] : E1[96+c-4];
      reinterpret_cast<float*>(er0+80)[c] = v0;
      reinterpret_cast<float*>(er1+80)[c] = v1;
    }
  }
}

// ============ edge value pass B: 2 edges/group, bf16 in/out =================
#define CB_VLS  0      // [64][52]
#define CB_VLVA 3328   // [32][36]
#define CB_VLVB 4480   // [32][20]
#define CB_VLVC 5120   // [32][20]
#define CB_W2   5760   // [112]
#define CB_EDG  5872
#define CB_ESTR 240

__global__ __launch_bounds__(256) void k_edgeCb(
    const float* __restrict__ Wvls, const float* __restrict__ Wvlv,
    const float* __restrict__ w2, const unsigned short* __restrict__ wa,
    unsigned short* __restrict__ wb)
{
  __shared__ __align__(16) float SH[CB_EDG + 16*CB_ESTR];
  const int t = threadIdx.x;
  for (int i=t; i<64*48; i+=256){ int d=i/48, k=i-48*d; SH[CB_VLS+d*52+k] = Wvls[k*64+d]; }
  for (int i=t; i<32*32; i+=256){ int d=i>>5, k=i&31; SH[CB_VLVA+d*36+k] = Wvlv[k*32+d]; }
  for (int i=t; i<32*16; i+=256){ int d=i>>4, k=i&15; SH[CB_VLVB+d*20+k] = Wvlv[(32+k)*32+d]; }
  for (int i=t; i<32*16; i+=256){ int d=i>>4, k=i&15; SH[CB_VLVC+d*20+k] = Wvlv[(48+k)*32+d]; }
  for (int i=t; i<112;   i+=256){ SH[CB_W2+i] = w2[i]; }
  __syncthreads();

  const int g = t >> 5;
  const int c = t & 31;
  float* E0 = &SH[CB_EDG + (2*g)*CB_ESTR];
  float* E1 = E0 + CB_ESTR;
  const float IS3 = 0.57735026918962576f;
  const float IS2 = 0.70710678118654752f;

#pragma unroll 1
  for (int tile=0; tile<8; ++tile){
    const int p0 = blockIdx.x*128 + tile*16 + 2*g;
    const int p1 = p0 + 1;
    const unsigned short* wr0 = wa + (size_t)p0*96;
    const unsigned short* wr1 = wa + (size_t)p1*96;

    const float vs0 = bf2f(wr0[c]);
    const float vs1 = bf2f(wr1[c]);
    E0[c] = bf2f(wr0[32+c]);      E1[c] = bf2f(wr1[32+c]);
    if (c < 16){ E0[32+c] = bf2f(wr0[64+c]); E1[32+c] = bf2f(wr1[64+c]); }
    if (c < 8) {
      E0[48+c] = reinterpret_cast<const float*>(wr0+80)[c];
      E1[48+c] = reinterpret_cast<const float*>(wr1+80)[c];
    }

    const float ya0=E0[52], yax=E0[53], yay=E0[54], yaz=E0[55];
    const float yb0=E1[52], ybx=E1[53], yby=E1[54], ybz=E1[55];

    const float w2t = SH[CB_W2+32+c], w2s = SH[CB_W2+c];
    E0[104+c] = w2t*vs0;          E1[104+c] = w2t*vs1;
    E0[56+c]  = w2s*vs0*ya0;      E1[56+c]  = w2s*vs1*yb0;
    if (c >= 16){
      int k = c-16;
      float w2d = SH[CB_W2+80+k];
      float gx=E0[k*3], gy=E0[k*3+1], gz=E0[k*3+2];
      E0[88+k] = w2d*(gx*yax+gy*yay+gz*yaz)*IS3;
      float hx=E1[k*3], hy=E1[k*3+1], hz=E1[k*3+2];
      E1[88+k] = w2d*(hx*ybx+hy*yby+hz*ybz)*IS3;
    }
    if (c < 16){
      int k = c;
      float w2v = SH[CB_W2+64+k], wq = SH[CB_W2+96+k];
      float gx=E0[k*3], gy=E0[k*3+1], gz=E0[k*3+2];
      float u0 = w2v*ya0;
      E0[136+k]=u0*gx; E0[152+k]=u0*gy; E0[168+k]=u0*gz;
      float cx=(gy*yaz - gz*yay)*IS2;
      float cy=(gz*yax - gx*yaz)*IS2;
      float cz=(gx*yay - gy*yax)*IS2;
      E0[184+k]=wq*cx; E0[200+k]=wq*cy; E0[216+k]=wq*cz;
      float hx=E1[k*3], hy=E1[k*3+1], hz=E1[k*3+2];
      float u1 = w2v*yb0;
      E1[136+k]=u1*hx; E1[152+k]=u1*hy; E1[168+k]=u1*hz;
      float dx=(hy*ybz - hz*yby)*IS2;
      float dy=(hz*ybx - hx*ybz)*IS2;
      float dz=(hx*yby - hy*ybx)*IS2;
      E1[184+k]=wq*dx; E1[200+k]=wq*dy; E1[216+k]=wq*dz;
    }

    const float a00=E0[48], a01=E0[49], a02=E0[50], a03=E0[51];
    const float a10=E1[48], a11=E1[49], a12=E1[50], a13=E1[51];

    unsigned short* ob0 = wb + (size_t)p0*160;
    unsigned short* ob1 = wb + (size_t)p1*160;

    {
      float f00=0.f, f01=0.f, f10=0.f, f11=0.f;
#pragma unroll
      for (int k4=0;k4<12;++k4){
        float4 wa4 = *reinterpret_cast<const float4*>(&SH[CB_VLS + c*52 + k4*4]);
        float4 wb4 = *reinterpret_cast<const float4*>(&SH[CB_VLS + (32+c)*52 + k4*4]);
        float4 v0 = *reinterpret_cast<const float4*>(&E0[56+k4*4]);
        float4 v1 = *reinterpret_cast<const float4*>(&E1[56+k4*4]);
        f00 += dot4(v0,wa4); f01 += dot4(v0,wb4);
        f10 += dot4(v1,wa4); f11 += dot4(v1,wb4);
      }
      ob0[c]    = f2bf(f00*a00);
      ob0[32+c] = f2bf(f01*((c<8)?a00:a01));
      ob1[c]    = f2bf(f10*a10);
      ob1[32+c] = f2bf(f11*((c<8)?a10:a11));
    }

    {
      float A20=0.f, A21=0.f;
#pragma unroll
      for (int k4=0;k4<8;++k4){
        float4 w = *reinterpret_cast<const float4*>(&SH[CB_VLVA + c*36 + k4*4]);
        float4 t0 = *reinterpret_cast<const float4*>(&E0[104+k4*4]);
        float4 t1 = *reinterpret_cast<const float4*>(&E1[104+k4*4]);
        A20 += dot4(t0,w); A21 += dot4(t1,w);
      }
      float b00=A20*yax, b01=A20*yay, b02=A20*yaz;
      float b10=A21*ybx, b11=A21*yby, b12=A21*ybz;
#pragma unroll
      for (int k4=0;k4<4;++k4){
        float4 wb4 = *reinterpret_cast<const float4*>(&SH[CB_VLVB + c*20 + k4*4]);
        float4 wc4 = *reinterpret_cast<const float4*>(&SH[CB_VLVC + c*20 + k4*4]);
        float4 p00 = *reinterpret_cast<const float4*>(&E0[136 + k4*4]);
        float4 p01 = *reinterpret_cast<const float4*>(&E0[152 + k4*4]);
        float4 p02 = *reinterpret_cast<const float4*>(&E0[168 + k4*4]);
        float4 q00 = *reinterpret_cast<const float4*>(&E0[184 + k4*4]);
        float4 q01 = *reinterpret_cast<const float4*>(&E0[200 + k4*4]);
        float4 q02 = *reinterpret_cast<const float4*>(&E0[216 + k4*4]);
        float4 p10 = *reinterpret_cast<const float4*>(&E1[136 + k4*4]);
        float4 p11 = *reinterpret_cast<const float4*>(&E1[152 + k4*4]);
        float4 p12 = *reinterpret_cast<const float4*>(&E1[168 + k4*4]);
        float4 q10 = *reinterpret_cast<const float4*>(&E1[184 + k4*4]);
        float4 q11 = *reinterpret_cast<const float4*>(&E1[200 + k4*4]);
        float4 q12 = *reinterpret_cast<const float4*>(&E1[216 + k4*4]);
        b00 += dot4(p00,wb4) + dot4(q00,wc4);
        b01 += dot4(p01,wb4) + dot4(q01,wc4);
        b02 += dot4(p02,wb4) + dot4(q02,wc4);
        b10 += dot4(p10,wb4) + dot4(q10,wc4);
        b11 += dot4(p11,wb4) + dot4(q11,wc4);
        b12 += dot4(p12,wb4) + dot4(q12,wc4);
      }
      int o = 64 + c*3;
      float aw00 = (o   < 80) ? a01 : ((o   < 120) ? a02 : a03);
      float aw01 = (o+1 < 80) ? a01 : ((o+1 < 120) ? a02 : a03);
      float aw02 = (o+2 < 80) ? a01 : ((o+2 < 120) ? a02 : a03);
      float aw10 = (o   < 80) ? a11 : ((o   < 120) ? a12 : a13);
      float aw11 = (o+1 < 80) ? a11 : ((o+1 < 120) ? a12 : a13);
      float aw12 = (o+2 < 80) ? a11 : ((o+2 < 120) ? a12 : a13);
      ob0[o]   = f2bf(b00*aw00);
      ob0[o+1] = f2bf(b01*aw01);
      ob0[o+2] = f2bf(b02*aw02);
      ob1[o]   = f2bf(b10*aw10);
      ob1[o+1] = f2bf(b11*aw11);
      ob1[o+2] = f2bf(b12*aw12);
    }
  }
}

// ------------- gather: per-dst sum of bf16 per-edge rows -------------------
__global__ __launch_bounds__(256) void k_gather(
    const int* __restrict__ base, const int* __restrict__ deg,
    const unsigned short* __restrict__ wb, float* __restrict__ agg)
{
  int id = blockIdx.x*256 + threadIdx.x;
  if (id >= NN*20) return;
  int d = id / 20, c = id % 20;
  int b = base[d], n = deg[d];
  float a0=0.f,a1=0.f,a2=0.f,a3=0.f,a4=0.f,a5=0.f,a6=0.f,a7=0.f;
  for (int i=0;i<n;++i){
    uint4 r = *reinterpret_cast<const uint4*>(wb + (size_t)(b+i)*160 + c*8);
    a0 += bf2f((unsigned short)(r.x & 0xFFFF));
    a1 += bf2f((unsigned short)(r.x >> 16));
    a2 += bf2f((unsigned short)(r.y & 0xFFFF));
    a3 += bf2f((unsigned short)(r.y >> 16));
    a4 += bf2f((unsigned short)(r.z & 0xFFFF));
    a5 += bf2f((unsigned short)(r.z >> 16));
    a6 += bf2f((unsigned short)(r.w & 0xFFFF));
    a7 += bf2f((unsigned short)(r.w >> 16));
  }
  float* ar = agg + (size_t)d*160 + c*8;
  float4 o0; o0.x=a0; o0.y=a1; o0.z=a2; o0.w=a3;
  float4 o1; o1.x=a4; o1.y=a5; o1.z=a6; o1.w=a7;
  reinterpret_cast<float4*>(ar)[0] = o0;
  reinterpret_cast<float4*>(ar)[1] = o1;
}

// ------------- output pass: Wp projections + residual ----------------------
__global__ __launch_bounds__(256) void k_out(
    const float* __restrict__ node, const float* __restrict__ agg,
    const float* __restrict__ Wps, const float* __restrict__ Wpv,
    float* __restrict__ out)
{
  int n = blockIdx.x * 256 + threadIdx.x;
  if (n >= NN) return;
  const float* ar = agg + (size_t)n*160;
  const float* nr = node + (size_t)n*80;
  float* orow = out + (size_t)n*80;

  float a[64];
  { const float4* ap = reinterpret_cast<const float4*>(ar);
#pragma unroll
    for (int i=0;i<16;++i){ float4 t=ap[i];
      a[i*4]=t.x; a[i*4+1]=t.y; a[i*4+2]=t.z; a[i*4+3]=t.w; } }
#pragma unroll 1
  for (int d=0; d<32; ++d){
    float acc=0.f;
#pragma unroll
    for (int c=0;c<64;++c) acc += a[c]*Wps[c*32+d];
    orow[d] = nr[d] + acc;
  }
  float b[96];
  { const float4* bp = reinterpret_cast<const float4*>(ar + 64);
#pragma unroll
    for (int i=0;i<24;++i){ float4 t=bp[i];
      b[i*4]=t.x; b[i*4+1]=t.y; b[i*4+2]=t.z; b[i*4+3]=t.w; } }
#pragma unroll 1
  for (int d=0; d<16; ++d){
#pragma unroll
    for (int x=0;x<3;++x){
      float acc=0.f;
#pragma unroll
      for (int c=0;c<32;++c) acc += b[c*3+x]*Wpv[c*16+d];
      orow[32+d*3+x] = nr[32+d*3+x] + acc;
    }
  }
}

extern "C" void kernel_launch(void* const* d_in, const int* in_sizes, int n_in,
                              void* d_out, int out_size, void* d_ws, size_t ws_size,
                              hipStream_t stream)
{
  const float* node   = (const float*)d_in[0];
  const float* rbf    = (const float*)d_in[1];
  const float* rsh    = (const float*)d_in[2];
  const float* Wsrc_s = (const float*)d_in[3];
  const float* Wsrc_v = (const float*)d_in[4];
  const float* Wdst_s = (const float*)d_in[5];
  const float* Wdst_v = (const float*)d_in[6];
  const float* W_rbf  = (const float*)d_in[7];
  const float* dtp2   = (const float*)d_in[8];
  const float* Wa     = (const float*)d_in[9];
  const float* adot   = (const float*)d_in[10];
  const float* Wval_s = (const float*)d_in[11];
  const float* Wval_v = (const float*)d_in[12];
  const float* Wg     = (const float*)d_in[13];
  const float* Wvl_s  = (const float*)d_in[14];
  const float* Wvl_v  = (const float*)d_in[15];
  const float* Wp_s   = (const float*)d_in[16];
  const float* Wp_v   = (const float*)d_in[17];
  const int*   ei     = (const int*)d_in[18];

  float* ws = (float*)d_ws;

  size_t off = 0;
  float* ss   = ws + off; off += (size_t)NN*32;
  float* ds   = ws + off; off += (size_t)NN*32;
  float* sv   = ws + off; off += (size_t)NN*48;
  float* dv   = ws + off; off += (size_t)NN*48;
  float* lg   = ws + off; off += (size_t)EE*4;
  float* m    = ws + off; off += (size_t)NN*4;
  float* iden = ws + off; off += (size_t)NN*4;
  int* deg    = (int*)(ws + off); off += (size_t)NN;
  int* base   = (int*)(ws + off); off += (size_t)NN;
  int* cursor = (int*)(ws + off); off += (size_t)NN;
  int* csr    = (int*)(ws + off); off += (size_t)EE;
  float* agg  = ws + off; off += (size_t)NN*160;
  unsigned short* wa = (unsigned short*)(ws + off); off += (size_t)EE*48;  // E*96 bf16
  unsigned short* wb = (unsigned short*)(ws + off); off += (size_t)EE*80;  // E*160 bf16
  size_t need_new = off * sizeof(float);
  if (ws_size < need_new) return;

  hipMemsetAsync(deg, 0, (size_t)NN*sizeof(int), stream);
  k_node   <<<NN/256, 256, 0, stream>>>(node, Wsrc_s, Wsrc_v, Wdst_s, Wdst_v, ss, ds, sv, dv);
  k_hist   <<<EE/256, 256, 0, stream>>>(ei, deg);
  k_scan   <<<1, 1024, 0, stream>>>(deg, base, cursor);
  k_scatter<<<EE/256, 256, 0, stream>>>(ei, cursor, csr);
  k_edgeA2 <<<EE/256, 512, 0, stream>>>(ei, rbf, rsh, W_rbf, Wa, adot, ss, ds, sv, dv, lg);
  k_soft   <<<(NN*4)/256, 256, 0, stream>>>(base, deg, csr, lg, m, iden);
  k_edgeCa <<<EE/128, 256, 0, stream>>>(csr, ei, rbf, rsh, W_rbf, Wval_s, Wval_v, Wg,
                                        ss, ds, sv, dv, lg, m, iden, wa);
  k_edgeCb <<<EE/128, 256, 0, stream>>>(Wvl_s, Wvl_v, dtp2, wa, wb);
  k_gather <<<(NN*20 + 255)/256, 256, 0, stream>>>(base, deg, wb, agg);
  k_out    <<<NN/256, 256, 0, stream>>>(node, agg, Wp_s, Wp_v, (float*)d_out);
}